// Round 2
// baseline (5448.874 us; speedup 1.0000x reference)
//
#include <hip/hip_runtime.h>
#include <math.h>

// HGNNPBlock: per-sample kNN hypergraph (k=30) + 2x (theta -> bn -> v2v mean).
// B=8, L=56*56=3136, C=64, hid=32.
//
// kNN strategy (R2): bf16 hi/lo split MFMA gram (hh+hl+lh, ~2e-4 d2 error)
// -> per-chunk approx top-32 heaps -> exact fp64 rescore of 224 candidates
// -> exact top-30 (same neighbor sets as the R1 fp64 kernel that passed).

namespace {

constexpr int cB = 8;
constexpr int cL = 3136;
constexpr int cC = 64;
constexpr int cH = 32;
constexpr int cK = 30;
constexpr int NV = cB * cL;        // 25088
constexpr int KC = 32;             // heap capacity per (row, chunk)
constexpr int NCH = 7;             // col chunks of 448 = 7*64
constexpr int CPR = NCH * KC;      // 224 candidates per row
constexpr float BN_SC = 0.99999500003749964f;  // 1/sqrt(1+1e-5) in fp32

typedef __bf16 bf16x4 __attribute__((ext_vector_type(4)));
typedef __bf16 bf16x8 __attribute__((ext_vector_type(8)));
typedef float floatx4 __attribute__((ext_vector_type(4)));

// ---------------- K0: split x into bf16 hi/lo + fp32 |x|^2 ----------------
__global__ void k_split(const float* __restrict__ x, ushort* __restrict__ xhi,
                        ushort* __restrict__ xlo, float* __restrict__ sqf) {
  int v = blockIdx.x * 256 + threadIdx.x;
  if (v >= NV) return;
  const float4* p = reinterpret_cast<const float4*>(x) + (size_t)v * 16;
  double s = 0.0;
#pragma unroll
  for (int c = 0; c < 16; ++c) {
    float4 f = p[c];
    bf16x4 hh, ll;
#pragma unroll
    for (int e = 0; e < 4; ++e) {
      float a = (&f.x)[e];
      __bf16 h = (__bf16)a;
      float hf = (float)h;
      __bf16 l = (__bf16)(a - hf);
      hh[e] = h;
      ll[e] = l;
      s += (double)a * (double)a;
    }
    *reinterpret_cast<bf16x4*>(&xhi[(size_t)v * 64 + c * 4]) = hh;
    *reinterpret_cast<bf16x4*>(&xlo[(size_t)v * 64 + c * 4]) = ll;
  }
  sqf[v] = (float)s;  // fp64-accumulated -> fp32 exact to ~4e-6
}

// ---------------- K1: MFMA gram + per-chunk top-32 ----------------
__device__ inline void heap_insertf(float* H, int* HI, float v, int idx) {
  if (v >= H[0]) return;  // re-check vs live root
  int pos = 0;
  while (true) {
    int c = 2 * pos + 1;
    if (c >= KC) break;
    float hc = H[c];
    int cc = c;
    if (c + 1 < KC) {
      float h2 = H[c + 1];
      if (h2 > hc) { hc = h2; cc = c + 1; }
    }
    if (hc <= v) break;
    H[pos] = hc; HI[pos] = HI[cc]; pos = cc;
  }
  H[pos] = v; HI[pos] = idx;
}

// grid (49, 7, 8): x = 64-row block, y = 448-col chunk, z = sample.
// block = 256 (4 waves); wave w owns rows w*16..w*16+15 (heaps wave-private).
__global__ __launch_bounds__(256) void k_knn2(const ushort* __restrict__ xhi,
                                              const ushort* __restrict__ xlo,
                                              const float* __restrict__ sqf,
                                              ushort* __restrict__ cand) {
  const int ib = blockIdx.x, ch = blockIdx.y, b = blockIdx.z;
  const int i0 = ib * 64;
  const int jc = ch * 448;
  const size_t bbase = (size_t)b * cL;

  // row stride 72 shorts (144 B): frag reads conflict-free per 8-lane phase
  __shared__ ushort aHi[64 * 72], aLo[64 * 72];
  __shared__ ushort bHi[64 * 72], bLo[64 * 72];
  __shared__ float hv[64 * 33];   // heap keys, stride 33 (root reads spread)
  __shared__ int   hx[64 * 33];
  __shared__ float sqJs[64];

  const int t  = threadIdx.x;
  const int ln = t & 63;
  const int w  = t >> 6;
  const int tx = ln & 15;
  const int qd = ln >> 4;

  // stage A tiles (hi+lo): 8 threads per 128B row -> coalesced
#pragma unroll
  for (int it = 0; it < 2; ++it) {
    int idx = t + 256 * it;
    int r = idx >> 3, blk = idx & 7;
    *reinterpret_cast<uint4*>(&aHi[r * 72 + blk * 8]) =
        *reinterpret_cast<const uint4*>(&xhi[(bbase + i0 + r) * 64 + blk * 8]);
    *reinterpret_cast<uint4*>(&aLo[r * 72 + blk * 8]) =
        *reinterpret_cast<const uint4*>(&xlo[(bbase + i0 + r) * 64 + blk * 8]);
  }
  for (int n = t; n < 64 * 33; n += 256) { hv[n] = 3.0e38f; hx[n] = 0; }
  __syncthreads();

  // A fragments are loop-invariant: 4 frags (hi/lo x k-halves), 16 VGPRs
  bf16x8 aH[2], aL[2];
#pragma unroll
  for (int kk = 0; kk < 2; ++kk) {
    aH[kk] = *reinterpret_cast<const bf16x8*>(
        &aHi[(w * 16 + tx) * 72 + kk * 32 + qd * 8]);
    aL[kk] = *reinterpret_cast<const bf16x8*>(
        &aLo[(w * 16 + tx) * 72 + kk * 32 + qd * 8]);
  }

  for (int st = 0; st < NCH; ++st) {
    const int jb = jc + st * 64;
#pragma unroll
    for (int it = 0; it < 2; ++it) {
      int idx = t + 256 * it;
      int r = idx >> 3, blk = idx & 7;
      *reinterpret_cast<uint4*>(&bHi[r * 72 + blk * 8]) =
          *reinterpret_cast<const uint4*>(&xhi[(bbase + jb + r) * 64 + blk * 8]);
      *reinterpret_cast<uint4*>(&bLo[r * 72 + blk * 8]) =
          *reinterpret_cast<const uint4*>(&xlo[(bbase + jb + r) * 64 + blk * 8]);
    }
    if (t < 64) sqJs[t] = sqf[bbase + jb + t];
    __syncthreads();

    float root[4];
#pragma unroll
    for (int e = 0; e < 4; ++e) root[e] = hv[(w * 16 + qd * 4 + e) * 33];

    unsigned pm = 0;
    float d2v[4][4];
#pragma unroll
    for (int f = 0; f < 4; ++f) {
      const int bro = (f * 16 + tx) * 72 + qd * 8;
      bf16x8 bh0 = *reinterpret_cast<const bf16x8*>(&bHi[bro]);
      bf16x8 bh1 = *reinterpret_cast<const bf16x8*>(&bHi[bro + 32]);
      bf16x8 bl0 = *reinterpret_cast<const bf16x8*>(&bLo[bro]);
      bf16x8 bl1 = *reinterpret_cast<const bf16x8*>(&bLo[bro + 32]);
      floatx4 acc = {0.f, 0.f, 0.f, 0.f};
      acc = __builtin_amdgcn_mfma_f32_16x16x32_bf16(aH[0], bh0, acc, 0, 0, 0);
      acc = __builtin_amdgcn_mfma_f32_16x16x32_bf16(aH[1], bh1, acc, 0, 0, 0);
      acc = __builtin_amdgcn_mfma_f32_16x16x32_bf16(aH[0], bl0, acc, 0, 0, 0);
      acc = __builtin_amdgcn_mfma_f32_16x16x32_bf16(aH[1], bl1, acc, 0, 0, 0);
      acc = __builtin_amdgcn_mfma_f32_16x16x32_bf16(aL[0], bh0, acc, 0, 0, 0);
      acc = __builtin_amdgcn_mfma_f32_16x16x32_bf16(aL[1], bh1, acc, 0, 0, 0);
      const float sj = sqJs[f * 16 + tx];
#pragma unroll
      for (int e = 0; e < 4; ++e) {
        // row-constant |xi|^2 dropped: within-row ranks unaffected
        float d2 = sj - 2.0f * acc[e];
        d2v[f][e] = d2;
        if (d2 < root[e]) pm |= 1u << (f * 4 + e);
      }
    }

    if (__ballot(pm != 0)) {
      // serialize across tx: active lanes (one per quad) hit distinct rows
      for (int s = 0; s < 16; ++s) {
        if (tx == s && pm) {
#pragma unroll
          for (int f = 0; f < 4; ++f)
#pragma unroll
            for (int e = 0; e < 4; ++e)
              if (pm & (1u << (f * 4 + e))) {
                const int lrow = w * 16 + qd * 4 + e;
                heap_insertf(&hv[lrow * 33], &hx[lrow * 33], d2v[f][e],
                             jb + f * 16 + tx);
              }
        }
      }
    }
    __syncthreads();  // protect B tiles + heap dump
  }

  for (int n = t; n < 64 * KC; n += 256) {
    int r = n >> 5, e = n & 31;
    cand[(bbase + i0 + r) * CPR + ch * KC + e] = (ushort)hx[r * 33 + e];
  }
}

// ---------------- K2: exact fp64 rescore of 224 candidates -> top-30 ------
__global__ __launch_bounds__(256) void k_rescore(const float* __restrict__ x,
                                                 const ushort* __restrict__ cand,
                                                 int* __restrict__ nbr) {
  const int w = threadIdx.x >> 6;
  const int ln = threadIdx.x & 63;
  const size_t row = (size_t)blockIdx.x * 4 + w;
  const int i = (int)(row % cL);
  const size_t bvert = row - i;  // b*cL

  float4 xi[16];
  const float4* xi4 = reinterpret_cast<const float4*>(x + row * 64);
#pragma unroll
  for (int c = 0; c < 16; ++c) xi[c] = xi4[c];

  const ushort* cr = cand + row * CPR;
  double dv[4];
  int jv[4];
#pragma unroll
  for (int s = 0; s < 4; ++s) { dv[s] = 1e300; jv[s] = 0; }

#pragma unroll
  for (int s = 0; s < 4; ++s) {
    int p = ln + 64 * s;
    if (p < CPR) {
      int j = cr[p];
      const float4* xj4 =
          reinterpret_cast<const float4*>(x + (bvert + j) * 64);
      double acc = 0.0;
#pragma unroll
      for (int c = 0; c < 16; ++c) {
        float4 xj = xj4[c];
        double d0 = (double)xi[c].x - (double)xj.x; acc = fma(d0, d0, acc);
        double d1 = (double)xi[c].y - (double)xj.y; acc = fma(d1, d1, acc);
        double d2 = (double)xi[c].z - (double)xj.z; acc = fma(d2, d2, acc);
        double d3 = (double)xi[c].w - (double)xj.w; acc = fma(d3, d3, acc);
      }
      dv[s] = acc;
      jv[s] = j;
    }
  }

  int* out = nbr + row * cK;
  for (int it = 0; it < cK; ++it) {
    double vmin = dv[0];
    int smin = 0;
#pragma unroll
    for (int s = 1; s < 4; ++s)
      if (dv[s] < vmin) { vmin = dv[s]; smin = s; }
    int code = (ln << 2) | smin;
#pragma unroll
    for (int off = 32; off; off >>= 1) {
      double ov = __shfl_xor(vmin, off);
      int oc = __shfl_xor(code, off);
      if (ov < vmin || (ov == vmin && oc < code)) { vmin = ov; code = oc; }
    }
    int wl = code >> 2, ws = code & 3;
    int jsel = jv[ws];              // uniform index -> register select
    int jwin = __shfl(jsel, wl);
    if (ln == 0) out[it] = jwin;
    if (ln == wl) dv[ws] = 1e300;   // remove winner
  }
}

// ---------------- CSR build (vertex -> edges containing it) ----------------
__global__ void k_count(const int* __restrict__ nbr, int* __restrict__ cnt) {
  int g = blockIdx.x * 256 + threadIdx.x;
  if (g >= NV * cK) return;
  int b = g / (cL * cK);
  atomicAdd(&cnt[b * cL + nbr[g]], 1);
}

__global__ void k_scan(const int* __restrict__ cnt, int* __restrict__ rp) {
  int b = blockIdx.x;
  int ln = threadIdx.x;  // block = 64 = one wave
  const int* c = cnt + b * cL;
  int* r = rp + b * (cL + 1);
  int carry = 0;
  for (int base = 0; base < cL; base += 64) {  // 3136 = 49*64 exact
    int v = c[base + ln];
    int s = v;
#pragma unroll
    for (int off = 1; off < 64; off <<= 1) {
      int u = __shfl_up(s, off);
      if (ln >= off) s += u;
    }
    r[base + ln] = carry + s - v;  // exclusive
    carry += __shfl(s, 63);
  }
  if (ln == 63) r[cL] = carry;
}

__global__ void k_fill(const int* __restrict__ nbr, const int* __restrict__ rp,
                       int* __restrict__ cur, int* __restrict__ el) {
  int g = blockIdx.x * 256 + threadIdx.x;
  if (g >= NV * cK) return;
  int b = g / (cL * cK);
  int e = (g / cK) % cL;
  int v = nbr[g];
  int p = rp[b * (cL + 1) + v] + atomicAdd(&cur[b * cL + v], 1);
  el[(size_t)b * cL * cK + p] = e;
}

// ---------------- theta + bn (eval) ----------------
__global__ __launch_bounds__(256) void k_theta1(const float* __restrict__ x,
                                                const float* __restrict__ w1,
                                                const float* __restrict__ b1,
                                                const float* __restrict__ g1,
                                                const float* __restrict__ be1,
                                                float* __restrict__ h1) {
  __shared__ float w[cC * cH];
  int t = threadIdx.x;
  for (int n = t; n < cC * cH; n += 256) w[n] = w1[n];
  __syncthreads();
  int g = blockIdx.x * 256 + t;
  int row = g >> 5;
  int f = g & 31;
  const float4* xr = reinterpret_cast<const float4*>(x) + (size_t)row * 16;
  float s = 0.f;
#pragma unroll
  for (int kc = 0; kc < 16; ++kc) {
    float4 xv = xr[kc];
    s += xv.x * w[(4 * kc + 0) * cH + f];
    s += xv.y * w[(4 * kc + 1) * cH + f];
    s += xv.z * w[(4 * kc + 2) * cH + f];
    s += xv.w * w[(4 * kc + 3) * cH + f];
  }
  h1[g] = (s + b1[f]) * (g1[f] * BN_SC) + be1[f];
}

__global__ __launch_bounds__(256) void k_theta2(const float* __restrict__ hin,
                                                const float* __restrict__ w2,
                                                const float* __restrict__ b2,
                                                const float* __restrict__ g2,
                                                const float* __restrict__ be2,
                                                float* __restrict__ h2) {
  __shared__ float w[cH * cC];
  int t = threadIdx.x;
  for (int n = t; n < cH * cC; n += 256) w[n] = w2[n];
  __syncthreads();
  int g = blockIdx.x * 256 + t;
  int row = g >> 6;
  int f = g & 63;
  const float4* hr = reinterpret_cast<const float4*>(hin) + (size_t)row * 8;
  float s = 0.f;
#pragma unroll
  for (int kc = 0; kc < 8; ++kc) {
    float4 hv4 = hr[kc];
    s += hv4.x * w[(4 * kc + 0) * cC + f];
    s += hv4.y * w[(4 * kc + 1) * cC + f];
    s += hv4.z * w[(4 * kc + 2) * cC + f];
    s += hv4.w * w[(4 * kc + 3) * cC + f];
  }
  h2[g] = (s + b2[f]) * (g2[f] * BN_SC) + be2[f];
}

// ---------------- v2e: mean over k neighbors ----------------
template <int F>
__global__ void k_v2e(const float* __restrict__ X, const int* __restrict__ nbr,
                      float* __restrict__ Y) {
  int g = blockIdx.x * 256 + threadIdx.x;
  int er = g / F;  // b*L + e
  int f  = g % F;
  int b  = er / cL;
  const int* nb = nbr + (size_t)er * cK;
  const float* Xb = X + (size_t)b * cL * F;
  float s = 0.f;
#pragma unroll 5
  for (int j = 0; j < cK; ++j) s += Xb[(size_t)nb[j] * F + f];
  Y[g] = s / 30.0f;
}

// ---------------- e2v: mean over incident edges (CSR) ----------------
template <int F, bool RELU>
__global__ void k_e2v(const float* __restrict__ Y, const int* __restrict__ rp,
                      const int* __restrict__ el, float* __restrict__ out) {
  int g = blockIdx.x * 256 + threadIdx.x;
  int vr = g / F;  // b*L + v
  int f  = g % F;
  int b  = vr / cL;
  int v  = vr % cL;
  const int* rpb = rp + b * (cL + 1);
  int s0 = rpb[v], s1 = rpb[v + 1];
  const int* elb = el + (size_t)b * cL * cK;
  const float* Yb = Y + (size_t)b * cL * F;
  float s = 0.f;
  for (int p = s0; p < s1; ++p) s += Yb[(size_t)elb[p] * F + f];
  int deg = s1 - s0;
  if (deg < 1) deg = 1;
  float r = s / (float)deg;
  if (RELU) r = fmaxf(r, 0.f);
  out[g] = r;
}

}  // namespace

extern "C" void kernel_launch(void* const* d_in, const int* in_sizes, int n_in,
                              void* d_out, int out_size, void* d_ws,
                              size_t ws_size, hipStream_t stream) {
  (void)in_sizes; (void)n_in; (void)out_size; (void)ws_size;
  const float* x   = (const float*)d_in[0];
  const float* w1  = (const float*)d_in[1];
  const float* b1  = (const float*)d_in[2];
  const float* g1  = (const float*)d_in[3];
  const float* be1 = (const float*)d_in[4];
  const float* w2  = (const float*)d_in[5];
  const float* b2  = (const float*)d_in[6];
  const float* g2  = (const float*)d_in[7];
  const float* be2 = (const float*)d_in[8];
  float* out = (float*)d_out;

  // workspace: ~24.5 MB peak via aliasing (<= R1's proven 27 MB)
  char* base = (char*)d_ws;
  size_t off = 0;
  auto carve = [&](size_t bytes) {
    char* p = base + off;
    off += (bytes + 255) & ~(size_t)255;
    return p;
  };
  float* sqf = (float*)carve((size_t)NV * 4);
  int*   nbr = (int*)carve((size_t)NV * cK * 4);
  int*   rp  = (int*)carve((size_t)cB * (cL + 1) * 4);
  // R4 union: {xhi|xlo} then {cnt|cur|el} (xhi/xlo dead after k_knn2)
  char* R4 = carve((size_t)NV * 64 * 2 * 2);  // 6,422,528
  ushort* xhi = (ushort*)R4;
  ushort* xlo = (ushort*)(R4 + 3211264);
  int* cnt = (int*)R4;
  int* cur = (int*)(R4 + 100608);
  int* el  = (int*)(R4 + 201216);
  // R5 union: cand (11.2 MB) then activation slots (cand dead after rescore)
  char* R5 = carve(16056320);
  ushort* cand = (ushort*)R5;
  float* h1  = (float*)R5;                 // slot1 (also h2)
  float* h2  = (float*)R5;
  float* Y1  = (float*)(R5 + 6422528);     // slot2 (also Y2)
  float* Y2  = (float*)(R5 + 6422528);
  float* h1v = (float*)(R5 + 12845056);    // slot3

  k_split<<<(NV + 255) / 256, 256, 0, stream>>>(x, xhi, xlo, sqf);
  k_knn2<<<dim3(cL / 64, NCH, cB), 256, 0, stream>>>(xhi, xlo, sqf, cand);
  k_rescore<<<NV / 4, 256, 0, stream>>>(x, cand, nbr);

  hipMemsetAsync(cnt, 0, (size_t)NV * 4, stream);
  hipMemsetAsync(cur, 0, (size_t)NV * 4, stream);
  k_count<<<(NV * cK) / 256, 256, 0, stream>>>(nbr, cnt);
  k_scan<<<cB, 64, 0, stream>>>(cnt, rp);
  k_fill<<<(NV * cK) / 256, 256, 0, stream>>>(nbr, rp, cur, el);

  k_theta1<<<NV * cH / 256, 256, 0, stream>>>(x, w1, b1, g1, be1, h1);
  k_v2e<cH><<<NV * cH / 256, 256, 0, stream>>>(h1, nbr, Y1);
  k_e2v<cH, true><<<NV * cH / 256, 256, 0, stream>>>(Y1, rp, el, h1v);
  k_theta2<<<NV * cC / 256, 256, 0, stream>>>(h1v, w2, b2, g2, be2, h2);
  k_v2e<cC><<<NV * cC / 256, 256, 0, stream>>>(h2, nbr, Y2);
  k_e2v<cC, false><<<NV * cC / 256, 256, 0, stream>>>(Y2, rp, el, out);
}

// Round 3
// 1417.574 us; speedup vs baseline: 3.8438x; 3.8438x over previous
//
#include <hip/hip_runtime.h>
#include <math.h>

// HGNNPBlock: per-sample kNN hypergraph (k=30) + 2x (theta -> bn -> v2v mean).
// B=8, L=56*56=3136, C=64, hid=32.
//
// R3 kNN pipeline: (1) MFMA hi/lo-bf16 gram -> approx d2 strips in ws (fp32),
// (2) per-row exact top-40 on approx d2 via register queues + wave-min
// extraction (no LDS heaps -- R2's regression), (3) exact fp64 rescore of the
// 40 candidates -> top-30 (same neighbor sets as the validated R1 kernel).

namespace {

constexpr int cB = 8;
constexpr int cL = 3136;
constexpr int cC = 64;
constexpr int cH = 32;
constexpr int cK = 30;
constexpr int NV = cB * cL;   // 25088
constexpr int CPR = 40;       // candidates per row (margin 10 over k=30)
constexpr float BN_SC = 0.99999500003749964f;  // 1/sqrt(1+1e-5) in fp32

typedef __bf16 bf16x4 __attribute__((ext_vector_type(4)));
typedef __bf16 bf16x8 __attribute__((ext_vector_type(8)));
typedef float floatx4 __attribute__((ext_vector_type(4)));

// ---------------- K0: split x into bf16 hi/lo + fp32 |x|^2 ----------------
__global__ void k_split(const float* __restrict__ x, ushort* __restrict__ xhi,
                        ushort* __restrict__ xlo, float* __restrict__ sqf) {
  int v = blockIdx.x * 256 + threadIdx.x;
  if (v >= NV) return;
  const float4* p = reinterpret_cast<const float4*>(x) + (size_t)v * 16;
  double s = 0.0;
#pragma unroll
  for (int c = 0; c < 16; ++c) {
    float4 f = p[c];
    bf16x4 hh, ll;
#pragma unroll
    for (int e = 0; e < 4; ++e) {
      float a = (&f.x)[e];
      __bf16 h = (__bf16)a;
      ll[e] = (__bf16)(a - (float)h);
      hh[e] = h;
      s += (double)a * (double)a;
    }
    *reinterpret_cast<bf16x4*>(&xhi[(size_t)v * 64 + c * 4]) = hh;
    *reinterpret_cast<bf16x4*>(&xlo[(size_t)v * 64 + c * 4]) = ll;
  }
  sqf[v] = (float)s;
}

// ---------------- K1: MFMA gram -> d2 strip (no selection) ----------------
// grid (rows/64, 49); block 256 (4 waves); wave w owns rows w*16..w*16+15.
// Fragment addressing identical to the R2 kernel (output validated).
__global__ __launch_bounds__(256) void k_gemm(const ushort* __restrict__ xhi,
                                              const ushort* __restrict__ xlo,
                                              const float* __restrict__ sqf,
                                              float* __restrict__ d2,
                                              int b, int row0) {
  const int jb = blockIdx.y * 64;
  const size_t bbase = (size_t)b * cL;
  const int r0 = row0 + blockIdx.x * 64;  // sample-local first row of A tile

  __shared__ ushort aHi[64 * 72], aLo[64 * 72];  // stride 72: conflict-free
  __shared__ ushort bHi[64 * 72], bLo[64 * 72];
  __shared__ float sqJs[64];

  const int t  = threadIdx.x;
  const int ln = t & 63;
  const int w  = t >> 6;
  const int tx = ln & 15;
  const int qd = ln >> 4;

#pragma unroll
  for (int it = 0; it < 2; ++it) {  // 512 row-slots of 8 shorts, 4 arrays
    int idx = t + 256 * it;
    int r = idx >> 3, blk = idx & 7;
    *reinterpret_cast<uint4*>(&aHi[r * 72 + blk * 8]) =
        *reinterpret_cast<const uint4*>(&xhi[(bbase + r0 + r) * 64 + blk * 8]);
    *reinterpret_cast<uint4*>(&aLo[r * 72 + blk * 8]) =
        *reinterpret_cast<const uint4*>(&xlo[(bbase + r0 + r) * 64 + blk * 8]);
    *reinterpret_cast<uint4*>(&bHi[r * 72 + blk * 8]) =
        *reinterpret_cast<const uint4*>(&xhi[(bbase + jb + r) * 64 + blk * 8]);
    *reinterpret_cast<uint4*>(&bLo[r * 72 + blk * 8]) =
        *reinterpret_cast<const uint4*>(&xlo[(bbase + jb + r) * 64 + blk * 8]);
  }
  if (t < 64) sqJs[t] = sqf[bbase + jb + t];
  __syncthreads();

  bf16x8 aH[2], aL[2];
#pragma unroll
  for (int kk = 0; kk < 2; ++kk) {
    aH[kk] = *reinterpret_cast<const bf16x8*>(
        &aHi[(w * 16 + tx) * 72 + kk * 32 + qd * 8]);
    aL[kk] = *reinterpret_cast<const bf16x8*>(
        &aLo[(w * 16 + tx) * 72 + kk * 32 + qd * 8]);
  }

#pragma unroll
  for (int f = 0; f < 4; ++f) {
    const int bro = (f * 16 + tx) * 72 + qd * 8;
    bf16x8 bh0 = *reinterpret_cast<const bf16x8*>(&bHi[bro]);
    bf16x8 bh1 = *reinterpret_cast<const bf16x8*>(&bHi[bro + 32]);
    bf16x8 bl0 = *reinterpret_cast<const bf16x8*>(&bLo[bro]);
    bf16x8 bl1 = *reinterpret_cast<const bf16x8*>(&bLo[bro + 32]);
    floatx4 acc = {0.f, 0.f, 0.f, 0.f};
    acc = __builtin_amdgcn_mfma_f32_16x16x32_bf16(aH[0], bh0, acc, 0, 0, 0);
    acc = __builtin_amdgcn_mfma_f32_16x16x32_bf16(aH[1], bh1, acc, 0, 0, 0);
    acc = __builtin_amdgcn_mfma_f32_16x16x32_bf16(aH[0], bl0, acc, 0, 0, 0);
    acc = __builtin_amdgcn_mfma_f32_16x16x32_bf16(aH[1], bl1, acc, 0, 0, 0);
    acc = __builtin_amdgcn_mfma_f32_16x16x32_bf16(aL[0], bh0, acc, 0, 0, 0);
    acc = __builtin_amdgcn_mfma_f32_16x16x32_bf16(aL[1], bh1, acc, 0, 0, 0);
    const float sj = sqJs[f * 16 + tx];
    const int col = jb + f * 16 + tx;
#pragma unroll
    for (int e = 0; e < 4; ++e) {
      // |xi|^2 dropped (row-constant): within-row ranks unaffected
      int row = blockIdx.x * 64 + w * 16 + qd * 4 + e;  // strip-local
      d2[(size_t)row * cL + col] = sj - 2.0f * acc[e];
    }
  }
}

// ---------------- K2: per-row exact top-40 on approx d2 ----------------
// One wave per row. Lane l scans cols {l+64i}; keeps sorted top-10 queue of
// packed u32 (monotone float bits[31:12] | col). 40 wave-min extractions.
__global__ __launch_bounds__(256) void k_select(const float* __restrict__ d2,
                                                ushort* __restrict__ cand) {
  const int w  = threadIdx.x >> 6;
  const int ln = threadIdx.x & 63;
  const int r  = blockIdx.x * 4 + w;  // strip-local row
  const float* row = d2 + (size_t)r * cL;

  unsigned q[10];
#pragma unroll
  for (int k = 0; k < 10; ++k) q[k] = 0xFFFFFFFFu;

  for (int i = 0; i < 49; ++i) {  // 3136 = 49*64
    const int col = ln + 64 * i;
    unsigned bits = __float_as_uint(row[col]);
    // monotone total-order map (handles tiny negative self-distances)
    unsigned u = bits ^ (0x80000000u | (unsigned)((int)bits >> 31));
    unsigned p = (u & 0xFFFFF000u) | (unsigned)col;  // col < 4096
    if (p < q[9]) {
      q[9] = p;
#pragma unroll
      for (int k = 9; k > 0; --k) {  // bubble the new element into place
        unsigned a = q[k - 1], c = q[k];
        q[k - 1] = min(a, c);
        q[k] = max(a, c);
      }
    }
  }

  ushort* cr = cand + (size_t)r * CPR;
  for (int it = 0; it < CPR; ++it) {
    unsigned h = q[0], m = h;
#pragma unroll
    for (int off = 32; off; off >>= 1)
      m = min(m, (unsigned)__shfl_xor((int)m, off));
    if (ln == 0) cr[it] = (ushort)(m & 0xFFFu);
    if (h == m) {  // unique winner (packed values distinct per col)
#pragma unroll
      for (int k = 0; k < 9; ++k) q[k] = q[k + 1];
      q[9] = 0xFFFFFFFFu;
    }
  }
}

// ---------------- K3: exact fp64 rescore of 40 candidates -> top-30 ------
__global__ __launch_bounds__(256) void k_rescore(const float* __restrict__ x,
                                                 const ushort* __restrict__ cand,
                                                 int* __restrict__ nbr) {
  const int w  = threadIdx.x >> 6;
  const int ln = threadIdx.x & 63;
  const size_t row = (size_t)blockIdx.x * 4 + w;
  const size_t bvert = row - (row % cL);  // b*cL

  float4 xi[16];
  const float4* xi4 = reinterpret_cast<const float4*>(x + row * 64);
#pragma unroll
  for (int c = 0; c < 16; ++c) xi[c] = xi4[c];

  double dv = 1e300;
  int jv = 0;
  if (ln < CPR) {
    int j = cand[row * CPR + ln];
    const float4* xj4 = reinterpret_cast<const float4*>(x + (bvert + j) * 64);
    double acc = 0.0;
#pragma unroll
    for (int c = 0; c < 16; ++c) {
      float4 xj = xj4[c];
      double d0 = (double)xi[c].x - (double)xj.x; acc = fma(d0, d0, acc);
      double d1 = (double)xi[c].y - (double)xj.y; acc = fma(d1, d1, acc);
      double d2 = (double)xi[c].z - (double)xj.z; acc = fma(d2, d2, acc);
      double d3 = (double)xi[c].w - (double)xj.w; acc = fma(d3, d3, acc);
    }
    dv = acc;
    jv = j;
  }

  int* out = nbr + row * cK;
  for (int it = 0; it < cK; ++it) {
    double vmin = dv;
    int code = ln;
#pragma unroll
    for (int off = 32; off; off >>= 1) {
      double ov = __shfl_xor(vmin, off);
      int oc = __shfl_xor(code, off);
      if (ov < vmin || (ov == vmin && oc < code)) { vmin = ov; code = oc; }
    }
    int jwin = __shfl(jv, code);
    if (ln == 0) out[it] = jwin;
    if (ln == code) dv = 1e300;
  }
}

// ---------------- CSR build (vertex -> edges containing it) ----------------
__global__ void k_count(const int* __restrict__ nbr, int* __restrict__ cnt) {
  int g = blockIdx.x * 256 + threadIdx.x;
  if (g >= NV * cK) return;
  int b = g / (cL * cK);
  atomicAdd(&cnt[b * cL + nbr[g]], 1);
}

__global__ void k_scan(const int* __restrict__ cnt, int* __restrict__ rp) {
  int b = blockIdx.x;
  int ln = threadIdx.x;  // block = 64 = one wave
  const int* c = cnt + b * cL;
  int* r = rp + b * (cL + 1);
  int carry = 0;
  for (int base = 0; base < cL; base += 64) {  // 3136 = 49*64
    int v = c[base + ln];
    int s = v;
#pragma unroll
    for (int off = 1; off < 64; off <<= 1) {
      int u = __shfl_up(s, off);
      if (ln >= off) s += u;
    }
    r[base + ln] = carry + s - v;  // exclusive
    carry += __shfl(s, 63);
  }
  if (ln == 63) r[cL] = carry;
}

__global__ void k_fill(const int* __restrict__ nbr, const int* __restrict__ rp,
                       int* __restrict__ cur, int* __restrict__ el) {
  int g = blockIdx.x * 256 + threadIdx.x;
  if (g >= NV * cK) return;
  int b = g / (cL * cK);
  int e = (g / cK) % cL;
  int v = nbr[g];
  int p = rp[b * (cL + 1) + v] + atomicAdd(&cur[b * cL + v], 1);
  el[(size_t)b * cL * cK + p] = e;
}

// ---------------- theta + bn (eval) ----------------
__global__ __launch_bounds__(256) void k_theta1(const float* __restrict__ x,
                                                const float* __restrict__ w1,
                                                const float* __restrict__ b1,
                                                const float* __restrict__ g1,
                                                const float* __restrict__ be1,
                                                float* __restrict__ h1) {
  __shared__ float w[cC * cH];
  int t = threadIdx.x;
  for (int n = t; n < cC * cH; n += 256) w[n] = w1[n];
  __syncthreads();
  int g = blockIdx.x * 256 + t;
  int row = g >> 5;
  int f = g & 31;
  const float4* xr = reinterpret_cast<const float4*>(x) + (size_t)row * 16;
  float s = 0.f;
#pragma unroll
  for (int kc = 0; kc < 16; ++kc) {
    float4 xv = xr[kc];
    s += xv.x * w[(4 * kc + 0) * cH + f];
    s += xv.y * w[(4 * kc + 1) * cH + f];
    s += xv.z * w[(4 * kc + 2) * cH + f];
    s += xv.w * w[(4 * kc + 3) * cH + f];
  }
  h1[g] = (s + b1[f]) * (g1[f] * BN_SC) + be1[f];
}

__global__ __launch_bounds__(256) void k_theta2(const float* __restrict__ hin,
                                                const float* __restrict__ w2,
                                                const float* __restrict__ b2,
                                                const float* __restrict__ g2,
                                                const float* __restrict__ be2,
                                                float* __restrict__ h2) {
  __shared__ float w[cH * cC];
  int t = threadIdx.x;
  for (int n = t; n < cH * cC; n += 256) w[n] = w2[n];
  __syncthreads();
  int g = blockIdx.x * 256 + t;
  int row = g >> 6;
  int f = g & 63;
  const float4* hr = reinterpret_cast<const float4*>(hin) + (size_t)row * 8;
  float s = 0.f;
#pragma unroll
  for (int kc = 0; kc < 8; ++kc) {
    float4 hv4 = hr[kc];
    s += hv4.x * w[(4 * kc + 0) * cC + f];
    s += hv4.y * w[(4 * kc + 1) * cC + f];
    s += hv4.z * w[(4 * kc + 2) * cC + f];
    s += hv4.w * w[(4 * kc + 3) * cC + f];
  }
  h2[g] = (s + b2[f]) * (g2[f] * BN_SC) + be2[f];
}

// ---------------- v2e: mean over k neighbors ----------------
template <int F>
__global__ void k_v2e(const float* __restrict__ X, const int* __restrict__ nbr,
                      float* __restrict__ Y) {
  int g = blockIdx.x * 256 + threadIdx.x;
  int er = g / F;  // b*L + e
  int f  = g % F;
  int b  = er / cL;
  const int* nb = nbr + (size_t)er * cK;
  const float* Xb = X + (size_t)b * cL * F;
  float s = 0.f;
#pragma unroll 5
  for (int j = 0; j < cK; ++j) s += Xb[(size_t)nb[j] * F + f];
  Y[g] = s / 30.0f;
}

// ---------------- e2v: mean over incident edges (CSR) ----------------
template <int F, bool RELU>
__global__ void k_e2v(const float* __restrict__ Y, const int* __restrict__ rp,
                      const int* __restrict__ el, float* __restrict__ out) {
  int g = blockIdx.x * 256 + threadIdx.x;
  int vr = g / F;  // b*L + v
  int f  = g % F;
  int b  = vr / cL;
  int v  = vr % cL;
  const int* rpb = rp + b * (cL + 1);
  int s0 = rpb[v], s1 = rpb[v + 1];
  const int* elb = el + (size_t)b * cL * cK;
  const float* Yb = Y + (size_t)b * cL * F;
  float s = 0.f;
  for (int p = s0; p < s1; ++p) s += Yb[(size_t)elb[p] * F + f];
  int deg = s1 - s0;
  if (deg < 1) deg = 1;
  float r = s / (float)deg;
  if (RELU) r = fmaxf(r, 0.f);
  out[g] = r;
}

}  // namespace

extern "C" void kernel_launch(void* const* d_in, const int* in_sizes, int n_in,
                              void* d_out, int out_size, void* d_ws,
                              size_t ws_size, hipStream_t stream) {
  (void)in_sizes; (void)n_in; (void)out_size; (void)ws_size;
  const float* x   = (const float*)d_in[0];
  const float* w1  = (const float*)d_in[1];
  const float* b1  = (const float*)d_in[2];
  const float* g1  = (const float*)d_in[3];
  const float* be1 = (const float*)d_in[4];
  const float* w2  = (const float*)d_in[5];
  const float* b2  = (const float*)d_in[6];
  const float* g2  = (const float*)d_in[7];
  const float* be2 = (const float*)d_in[8];
  float* out = (float*)d_out;

  // workspace: ~31.7 MB peak (R1 proved ~29 MB OK on this harness)
  char* base = (char*)d_ws;
  size_t off = 0;
  auto carve = [&](size_t bytes) {
    char* p = base + off;
    off += (bytes + 255) & ~(size_t)255;
    return p;
  };
  float*  sqf  = (float*)carve((size_t)NV * 4);
  int*    nbr  = (int*)carve((size_t)NV * cK * 4);
  int*    rp   = (int*)carve((size_t)cB * (cL + 1) * 4);
  ushort* cand = (ushort*)carve((size_t)NV * CPR * 2);
  // region A: {xhi|xlo} (dead after last k_gemm) then {cnt|cur|el}
  char* RA = carve((size_t)NV * 64 * 2 * 2);  // 6,422,528
  ushort* xhi = (ushort*)RA;
  ushort* xlo = (ushort*)(RA + 3211264);
  int* cnt = (int*)RA;
  int* cur = (int*)(RA + 100608);
  int* el  = (int*)(RA + 201216);
  // region B: d2 strip (dead after last k_select) then activations
  char* RB = carve((size_t)1600 * cL * 4);  // 20,070,400
  float* d2s = (float*)RB;
  float* h1  = (float*)RB;                 // slot1 (reused as h2)
  float* h2  = (float*)RB;
  float* Y1  = (float*)(RB + 6422528);     // slot2 (reused as Y2)
  float* Y2  = (float*)(RB + 6422528);
  float* h1v = (float*)(RB + 12845056);    // slot3

  k_split<<<(NV + 255) / 256, 256, 0, stream>>>(x, xhi, xlo, sqf);

  // 8 samples x 2 row-strips {1600, 1536}: gram -> d2 strip -> top-40
  for (int b = 0; b < cB; ++b) {
    for (int hhalf = 0; hhalf < 2; ++hhalf) {
      const int row0 = hhalf ? 1600 : 0;
      const int rows = hhalf ? 1536 : 1600;
      k_gemm<<<dim3(rows / 64, 49), 256, 0, stream>>>(xhi, xlo, sqf, d2s, b,
                                                      row0);
      k_select<<<rows / 4, 256, 0, stream>>>(
          d2s, cand + ((size_t)b * cL + row0) * CPR);
    }
  }
  k_rescore<<<NV / 4, 256, 0, stream>>>(x, cand, nbr);

  hipMemsetAsync(cnt, 0, (size_t)NV * 4, stream);
  hipMemsetAsync(cur, 0, (size_t)NV * 4, stream);
  k_count<<<(NV * cK) / 256, 256, 0, stream>>>(nbr, cnt);
  k_scan<<<cB, 64, 0, stream>>>(cnt, rp);
  k_fill<<<(NV * cK) / 256, 256, 0, stream>>>(nbr, rp, cur, el);

  k_theta1<<<NV * cH / 256, 256, 0, stream>>>(x, w1, b1, g1, be1, h1);
  k_v2e<cH><<<NV * cH / 256, 256, 0, stream>>>(h1, nbr, Y1);
  k_e2v<cH, true><<<NV * cH / 256, 256, 0, stream>>>(Y1, rp, el, h1v);
  k_theta2<<<NV * cC / 256, 256, 0, stream>>>(h1v, w2, b2, g2, be2, h2);
  k_v2e<cC><<<NV * cC / 256, 256, 0, stream>>>(h2, nbr, Y2);
  k_e2v<cC, false><<<NV * cC / 256, 256, 0, stream>>>(Y2, rp, el, out);
}

// Round 4
// 1146.359 us; speedup vs baseline: 4.7532x; 1.2366x over previous
//
#include <hip/hip_runtime.h>
#include <math.h>

// HGNNPBlock: per-sample kNN hypergraph (k=30) + 2x (theta -> bn -> v2v mean).
// B=8, L=56*56=3136, C=64, hid=32.
//
// R3 kNN pipeline (validated): MFMA hi/lo-bf16 gram -> approx d2 strips ->
// per-row exact top-40 (register queues + wave-min) -> fp64 rescore -> top-30.
// R4: v2e/e2v rewritten wave-per-row -- parallel index load + shfl broadcast
// turns 30 dependent gather pairs into 30 independent coalesced gathers
// (R3 counters: e2v 255us, VALUBusy 4%, HBM 2% -> pure latency-bound).

namespace {

constexpr int cB = 8;
constexpr int cL = 3136;
constexpr int cC = 64;
constexpr int cH = 32;
constexpr int cK = 30;
constexpr int NV = cB * cL;   // 25088
constexpr int CPR = 40;       // candidates per row (margin 10 over k=30)
constexpr float BN_SC = 0.99999500003749964f;  // 1/sqrt(1+1e-5) in fp32

typedef __bf16 bf16x4 __attribute__((ext_vector_type(4)));
typedef __bf16 bf16x8 __attribute__((ext_vector_type(8)));
typedef float floatx4 __attribute__((ext_vector_type(4)));

// ---------------- K0: split x into bf16 hi/lo + fp32 |x|^2 ----------------
__global__ void k_split(const float* __restrict__ x, ushort* __restrict__ xhi,
                        ushort* __restrict__ xlo, float* __restrict__ sqf) {
  int v = blockIdx.x * 256 + threadIdx.x;
  if (v >= NV) return;
  const float4* p = reinterpret_cast<const float4*>(x) + (size_t)v * 16;
  double s = 0.0;
#pragma unroll
  for (int c = 0; c < 16; ++c) {
    float4 f = p[c];
    bf16x4 hh, ll;
#pragma unroll
    for (int e = 0; e < 4; ++e) {
      float a = (&f.x)[e];
      __bf16 h = (__bf16)a;
      ll[e] = (__bf16)(a - (float)h);
      hh[e] = h;
      s += (double)a * (double)a;
    }
    *reinterpret_cast<bf16x4*>(&xhi[(size_t)v * 64 + c * 4]) = hh;
    *reinterpret_cast<bf16x4*>(&xlo[(size_t)v * 64 + c * 4]) = ll;
  }
  sqf[v] = (float)s;
}

// ---------------- K1: MFMA gram -> d2 strip (no selection) ----------------
// grid (rows/64, 49); block 256 (4 waves); wave w owns rows w*16..w*16+15.
__global__ __launch_bounds__(256) void k_gemm(const ushort* __restrict__ xhi,
                                              const ushort* __restrict__ xlo,
                                              const float* __restrict__ sqf,
                                              float* __restrict__ d2,
                                              int b, int row0) {
  const int jb = blockIdx.y * 64;
  const size_t bbase = (size_t)b * cL;
  const int r0 = row0 + blockIdx.x * 64;  // sample-local first row of A tile

  __shared__ ushort aHi[64 * 72], aLo[64 * 72];  // stride 72: conflict-free
  __shared__ ushort bHi[64 * 72], bLo[64 * 72];
  __shared__ float sqJs[64];

  const int t  = threadIdx.x;
  const int ln = t & 63;
  const int w  = t >> 6;
  const int tx = ln & 15;
  const int qd = ln >> 4;

#pragma unroll
  for (int it = 0; it < 2; ++it) {  // 512 row-slots of 8 shorts, 4 arrays
    int idx = t + 256 * it;
    int r = idx >> 3, blk = idx & 7;
    *reinterpret_cast<uint4*>(&aHi[r * 72 + blk * 8]) =
        *reinterpret_cast<const uint4*>(&xhi[(bbase + r0 + r) * 64 + blk * 8]);
    *reinterpret_cast<uint4*>(&aLo[r * 72 + blk * 8]) =
        *reinterpret_cast<const uint4*>(&xlo[(bbase + r0 + r) * 64 + blk * 8]);
    *reinterpret_cast<uint4*>(&bHi[r * 72 + blk * 8]) =
        *reinterpret_cast<const uint4*>(&xhi[(bbase + jb + r) * 64 + blk * 8]);
    *reinterpret_cast<uint4*>(&bLo[r * 72 + blk * 8]) =
        *reinterpret_cast<const uint4*>(&xlo[(bbase + jb + r) * 64 + blk * 8]);
  }
  if (t < 64) sqJs[t] = sqf[bbase + jb + t];
  __syncthreads();

  bf16x8 aH[2], aL[2];
#pragma unroll
  for (int kk = 0; kk < 2; ++kk) {
    aH[kk] = *reinterpret_cast<const bf16x8*>(
        &aHi[(w * 16 + tx) * 72 + kk * 32 + qd * 8]);
    aL[kk] = *reinterpret_cast<const bf16x8*>(
        &aLo[(w * 16 + tx) * 72 + kk * 32 + qd * 8]);
  }

#pragma unroll
  for (int f = 0; f < 4; ++f) {
    const int bro = (f * 16 + tx) * 72 + qd * 8;
    bf16x8 bh0 = *reinterpret_cast<const bf16x8*>(&bHi[bro]);
    bf16x8 bh1 = *reinterpret_cast<const bf16x8*>(&bHi[bro + 32]);
    bf16x8 bl0 = *reinterpret_cast<const bf16x8*>(&bLo[bro]);
    bf16x8 bl1 = *reinterpret_cast<const bf16x8*>(&bLo[bro + 32]);
    floatx4 acc = {0.f, 0.f, 0.f, 0.f};
    acc = __builtin_amdgcn_mfma_f32_16x16x32_bf16(aH[0], bh0, acc, 0, 0, 0);
    acc = __builtin_amdgcn_mfma_f32_16x16x32_bf16(aH[1], bh1, acc, 0, 0, 0);
    acc = __builtin_amdgcn_mfma_f32_16x16x32_bf16(aH[0], bl0, acc, 0, 0, 0);
    acc = __builtin_amdgcn_mfma_f32_16x16x32_bf16(aH[1], bl1, acc, 0, 0, 0);
    acc = __builtin_amdgcn_mfma_f32_16x16x32_bf16(aL[0], bh0, acc, 0, 0, 0);
    acc = __builtin_amdgcn_mfma_f32_16x16x32_bf16(aL[1], bh1, acc, 0, 0, 0);
    const float sj = sqJs[f * 16 + tx];
    const int col = jb + f * 16 + tx;
#pragma unroll
    for (int e = 0; e < 4; ++e) {
      // |xi|^2 dropped (row-constant): within-row ranks unaffected
      int row = blockIdx.x * 64 + w * 16 + qd * 4 + e;  // strip-local
      d2[(size_t)row * cL + col] = sj - 2.0f * acc[e];
    }
  }
}

// ---------------- K2: per-row exact top-40 on approx d2 ----------------
// One wave per row. Lane l scans cols {l+64i}; keeps sorted top-10 queue of
// packed u32 (monotone float bits[31:12] | col). 40 wave-min extractions.
__global__ __launch_bounds__(256) void k_select(const float* __restrict__ d2,
                                                ushort* __restrict__ cand) {
  const int w  = threadIdx.x >> 6;
  const int ln = threadIdx.x & 63;
  const int r  = blockIdx.x * 4 + w;  // strip-local row
  const float* row = d2 + (size_t)r * cL;

  unsigned q[10];
#pragma unroll
  for (int k = 0; k < 10; ++k) q[k] = 0xFFFFFFFFu;

  for (int i = 0; i < 49; ++i) {  // 3136 = 49*64
    const int col = ln + 64 * i;
    unsigned bits = __float_as_uint(row[col]);
    // monotone total-order map (handles tiny negative self-distances)
    unsigned u = bits ^ (0x80000000u | (unsigned)((int)bits >> 31));
    unsigned p = (u & 0xFFFFF000u) | (unsigned)col;  // col < 4096
    if (p < q[9]) {
      q[9] = p;
#pragma unroll
      for (int k = 9; k > 0; --k) {  // bubble the new element into place
        unsigned a = q[k - 1], c = q[k];
        q[k - 1] = min(a, c);
        q[k] = max(a, c);
      }
    }
  }

  ushort* cr = cand + (size_t)r * CPR;
  for (int it = 0; it < CPR; ++it) {
    unsigned h = q[0], m = h;
#pragma unroll
    for (int off = 32; off; off >>= 1)
      m = min(m, (unsigned)__shfl_xor((int)m, off));
    if (ln == 0) cr[it] = (ushort)(m & 0xFFFu);
    if (h == m) {  // unique winner (packed values distinct per col)
#pragma unroll
      for (int k = 0; k < 9; ++k) q[k] = q[k + 1];
      q[9] = 0xFFFFFFFFu;
    }
  }
}

// ---------------- K3: exact fp64 rescore of 40 candidates -> top-30 ------
__global__ __launch_bounds__(256) void k_rescore(const float* __restrict__ x,
                                                 const ushort* __restrict__ cand,
                                                 int* __restrict__ nbr) {
  const int w  = threadIdx.x >> 6;
  const int ln = threadIdx.x & 63;
  const size_t row = (size_t)blockIdx.x * 4 + w;
  const size_t bvert = row - (row % cL);  // b*cL

  float4 xi[16];
  const float4* xi4 = reinterpret_cast<const float4*>(x + row * 64);
#pragma unroll
  for (int c = 0; c < 16; ++c) xi[c] = xi4[c];

  double dv = 1e300;
  int jv = 0;
  if (ln < CPR) {
    int j = cand[row * CPR + ln];
    const float4* xj4 = reinterpret_cast<const float4*>(x + (bvert + j) * 64);
    double acc = 0.0;
#pragma unroll
    for (int c = 0; c < 16; ++c) {
      float4 xj = xj4[c];
      double d0 = (double)xi[c].x - (double)xj.x; acc = fma(d0, d0, acc);
      double d1 = (double)xi[c].y - (double)xj.y; acc = fma(d1, d1, acc);
      double d2 = (double)xi[c].z - (double)xj.z; acc = fma(d2, d2, acc);
      double d3 = (double)xi[c].w - (double)xj.w; acc = fma(d3, d3, acc);
    }
    dv = acc;
    jv = j;
  }

  int* out = nbr + row * cK;
  for (int it = 0; it < cK; ++it) {
    double vmin = dv;
    int code = ln;
#pragma unroll
    for (int off = 32; off; off >>= 1) {
      double ov = __shfl_xor(vmin, off);
      int oc = __shfl_xor(code, off);
      if (ov < vmin || (ov == vmin && oc < code)) { vmin = ov; code = oc; }
    }
    int jwin = __shfl(jv, code);
    if (ln == 0) out[it] = jwin;
    if (ln == code) dv = 1e300;
  }
}

// ---------------- CSR build (vertex -> edges containing it) ----------------
__global__ void k_count(const int* __restrict__ nbr, int* __restrict__ cnt) {
  int g = blockIdx.x * 256 + threadIdx.x;
  if (g >= NV * cK) return;
  int b = g / (cL * cK);
  atomicAdd(&cnt[b * cL + nbr[g]], 1);
}

__global__ void k_scan(const int* __restrict__ cnt, int* __restrict__ rp) {
  int b = blockIdx.x;
  int ln = threadIdx.x;  // block = 64 = one wave
  const int* c = cnt + b * cL;
  int* r = rp + b * (cL + 1);
  int carry = 0;
  for (int base = 0; base < cL; base += 64) {  // 3136 = 49*64
    int v = c[base + ln];
    int s = v;
#pragma unroll
    for (int off = 1; off < 64; off <<= 1) {
      int u = __shfl_up(s, off);
      if (ln >= off) s += u;
    }
    r[base + ln] = carry + s - v;  // exclusive
    carry += __shfl(s, 63);
  }
  if (ln == 63) r[cL] = carry;
}

__global__ void k_fill(const int* __restrict__ nbr, const int* __restrict__ rp,
                       int* __restrict__ cur, int* __restrict__ el) {
  int g = blockIdx.x * 256 + threadIdx.x;
  if (g >= NV * cK) return;
  int b = g / (cL * cK);
  int e = (g / cK) % cL;
  int v = nbr[g];
  int p = rp[b * (cL + 1) + v] + atomicAdd(&cur[b * cL + v], 1);
  el[(size_t)b * cL * cK + p] = e;
}

// ---------------- theta + bn (eval) ----------------
__global__ __launch_bounds__(256) void k_theta1(const float* __restrict__ x,
                                                const float* __restrict__ w1,
                                                const float* __restrict__ b1,
                                                const float* __restrict__ g1,
                                                const float* __restrict__ be1,
                                                float* __restrict__ h1) {
  __shared__ float w[cC * cH];
  int t = threadIdx.x;
  for (int n = t; n < cC * cH; n += 256) w[n] = w1[n];
  __syncthreads();
  int g = blockIdx.x * 256 + t;
  int row = g >> 5;
  int f = g & 31;
  const float4* xr = reinterpret_cast<const float4*>(x) + (size_t)row * 16;
  float s = 0.f;
#pragma unroll
  for (int kc = 0; kc < 16; ++kc) {
    float4 xv = xr[kc];
    s += xv.x * w[(4 * kc + 0) * cH + f];
    s += xv.y * w[(4 * kc + 1) * cH + f];
    s += xv.z * w[(4 * kc + 2) * cH + f];
    s += xv.w * w[(4 * kc + 3) * cH + f];
  }
  h1[g] = (s + b1[f]) * (g1[f] * BN_SC) + be1[f];
}

__global__ __launch_bounds__(256) void k_theta2(const float* __restrict__ hin,
                                                const float* __restrict__ w2,
                                                const float* __restrict__ b2,
                                                const float* __restrict__ g2,
                                                const float* __restrict__ be2,
                                                float* __restrict__ h2) {
  __shared__ float w[cH * cC];
  int t = threadIdx.x;
  for (int n = t; n < cH * cC; n += 256) w[n] = w2[n];
  __syncthreads();
  int g = blockIdx.x * 256 + t;
  int row = g >> 6;
  int f = g & 63;
  const float4* hr = reinterpret_cast<const float4*>(hin) + (size_t)row * 8;
  float s = 0.f;
#pragma unroll
  for (int kc = 0; kc < 8; ++kc) {
    float4 hv4 = hr[kc];
    s += hv4.x * w[(4 * kc + 0) * cC + f];
    s += hv4.y * w[(4 * kc + 1) * cC + f];
    s += hv4.z * w[(4 * kc + 2) * cC + f];
    s += hv4.w * w[(4 * kc + 3) * cC + f];
  }
  h2[g] = (s + b2[f]) * (g2[f] * BN_SC) + be2[f];
}

// ---------------- v2e: mean over k neighbors (wave per edge) ----------------
// One parallel 30-int index load + shfl broadcast -> 30 INDEPENDENT coalesced
// row gathers (R3's version chained dependent loads: 255us at 4% VALU).
template <int F>
__global__ __launch_bounds__(256) void k_v2e(const float* __restrict__ X,
                                             const int* __restrict__ nbr,
                                             float* __restrict__ Y) {
  const int w  = threadIdx.x >> 6;
  const int ln = threadIdx.x & 63;
  const size_t er = (size_t)blockIdx.x * 4 + w;  // b*cL + e
  const size_t b  = er / cL;
  const float* Xb = X + b * cL * F;
  const int* nb = nbr + er * cK;
  const int eidx = nb[ln < cK ? ln : cK - 1];  // one coalesced load
  float s = 0.f;
  if constexpr (F == 64) {
#pragma unroll
    for (int j = 0; j < cK; j += 5) {
      int e0 = __shfl(eidx, j + 0), e1 = __shfl(eidx, j + 1);
      int e2 = __shfl(eidx, j + 2), e3 = __shfl(eidx, j + 3);
      int e4 = __shfl(eidx, j + 4);
      float y0 = Xb[(size_t)e0 * 64 + ln], y1 = Xb[(size_t)e1 * 64 + ln];
      float y2 = Xb[(size_t)e2 * 64 + ln], y3 = Xb[(size_t)e3 * 64 + ln];
      float y4 = Xb[(size_t)e4 * 64 + ln];
      s += ((y0 + y1) + (y2 + y3)) + y4;
    }
    Y[er * 64 + ln] = s * (1.f / 30.f);
  } else {  // F == 32: both half-waves work, 2 neighbors per step
    const int hi = ln >> 5, f = ln & 31;
#pragma unroll
    for (int j = 0; j < cK; j += 6) {
      int e0 = __shfl(eidx, j + 0 + hi);
      int e1 = __shfl(eidx, j + 2 + hi);
      int e2 = __shfl(eidx, j + 4 + hi);
      float y0 = Xb[(size_t)e0 * 32 + f], y1 = Xb[(size_t)e1 * 32 + f];
      float y2 = Xb[(size_t)e2 * 32 + f];
      s += (y0 + y1) + y2;
    }
    s += __shfl_xor(s, 32);
    if (hi == 0) Y[er * 32 + f] = s * (1.f / 30.f);
  }
}

// ---------------- e2v: mean over incident edges (wave per vertex) ----------
template <int F, bool RELU>
__global__ __launch_bounds__(256) void k_e2v(const float* __restrict__ Y,
                                             const int* __restrict__ rp,
                                             const int* __restrict__ el,
                                             float* __restrict__ out) {
  const int w  = threadIdx.x >> 6;
  const int ln = threadIdx.x & 63;
  const size_t vr = (size_t)blockIdx.x * 4 + w;  // b*cL + v
  const size_t b  = vr / cL;
  const int v = (int)(vr % cL);
  const int* rpb = rp + b * (cL + 1);
  const int s0 = rpb[v];
  const int deg = rpb[v + 1] - s0;  // >= 1 (self edge always selected)
  const int* elb = el + b * (size_t)cL * cK + s0;
  const float* Yb = Y + b * cL * F;
  float s = 0.f;

  for (int base = 0; base < deg; base += 64) {
    const int take = min(64, deg - base);
    const int eidx = elb[base + (ln < take ? ln : 0)];  // parallel load
    if constexpr (F == 64) {
      int j = 0;
      for (; j + 4 <= take; j += 4) {
        int e0 = __shfl(eidx, j + 0), e1 = __shfl(eidx, j + 1);
        int e2 = __shfl(eidx, j + 2), e3 = __shfl(eidx, j + 3);
        float y0 = Yb[(size_t)e0 * 64 + ln], y1 = Yb[(size_t)e1 * 64 + ln];
        float y2 = Yb[(size_t)e2 * 64 + ln], y3 = Yb[(size_t)e3 * 64 + ln];
        s += (y0 + y1) + (y2 + y3);
      }
      for (; j < take; ++j) s += Yb[(size_t)__shfl(eidx, j) * 64 + ln];
    } else {  // F == 32
      const int hi = ln >> 5, f = ln & 31;
      int j = 0;
      for (; j + 4 <= take; j += 4) {
        int e0 = __shfl(eidx, j + 0 + hi);
        int e1 = __shfl(eidx, j + 2 + hi);
        s += Yb[(size_t)e0 * 32 + f] + Yb[(size_t)e1 * 32 + f];
      }
      for (; j < take; j += 2) {
        int jj = j + hi;
        int e0 = __shfl(eidx, jj < take ? jj : 0);
        float y = Yb[(size_t)e0 * 32 + f];
        s += (jj < take) ? y : 0.f;
      }
    }
  }

  if constexpr (F == 32) s += __shfl_xor(s, 32);
  float r = s / (float)deg;
  if (RELU) r = fmaxf(r, 0.f);
  if constexpr (F == 64) {
    out[vr * 64 + ln] = r;
  } else {
    if (ln < 32) out[vr * 32 + ln] = r;
  }
}

}  // namespace

extern "C" void kernel_launch(void* const* d_in, const int* in_sizes, int n_in,
                              void* d_out, int out_size, void* d_ws,
                              size_t ws_size, hipStream_t stream) {
  (void)in_sizes; (void)n_in; (void)out_size; (void)ws_size;
  const float* x   = (const float*)d_in[0];
  const float* w1  = (const float*)d_in[1];
  const float* b1  = (const float*)d_in[2];
  const float* g1  = (const float*)d_in[3];
  const float* be1 = (const float*)d_in[4];
  const float* w2  = (const float*)d_in[5];
  const float* b2  = (const float*)d_in[6];
  const float* g2  = (const float*)d_in[7];
  const float* be2 = (const float*)d_in[8];
  float* out = (float*)d_out;

  // workspace: ~31.7 MB peak (proven OK in R3)
  char* base = (char*)d_ws;
  size_t off = 0;
  auto carve = [&](size_t bytes) {
    char* p = base + off;
    off += (bytes + 255) & ~(size_t)255;
    return p;
  };
  float*  sqf  = (float*)carve((size_t)NV * 4);
  int*    nbr  = (int*)carve((size_t)NV * cK * 4);
  int*    rp   = (int*)carve((size_t)cB * (cL + 1) * 4);
  ushort* cand = (ushort*)carve((size_t)NV * CPR * 2);
  // region A: {xhi|xlo} (dead after last k_gemm) then {cnt|cur|el}
  char* RA = carve((size_t)NV * 64 * 2 * 2);  // 6,422,528
  ushort* xhi = (ushort*)RA;
  ushort* xlo = (ushort*)(RA + 3211264);
  int* cnt = (int*)RA;
  int* cur = (int*)(RA + 100608);
  int* el  = (int*)(RA + 201216);
  // region B: d2 strip (dead after last k_select) then activations
  char* RB = carve((size_t)1600 * cL * 4);  // 20,070,400
  float* d2s = (float*)RB;
  float* h1  = (float*)RB;                 // slot1 (reused as h2)
  float* h2  = (float*)RB;
  float* Y1  = (float*)(RB + 6422528);     // slot2 (reused as Y2)
  float* Y2  = (float*)(RB + 6422528);
  float* h1v = (float*)(RB + 12845056);    // slot3

  k_split<<<(NV + 255) / 256, 256, 0, stream>>>(x, xhi, xlo, sqf);

  // 8 samples x 2 row-strips {1600, 1536}: gram -> d2 strip -> top-40
  for (int b = 0; b < cB; ++b) {
    for (int hhalf = 0; hhalf < 2; ++hhalf) {
      const int row0 = hhalf ? 1600 : 0;
      const int rows = hhalf ? 1536 : 1600;
      k_gemm<<<dim3(rows / 64, 49), 256, 0, stream>>>(xhi, xlo, sqf, d2s, b,
                                                      row0);
      k_select<<<rows / 4, 256, 0, stream>>>(
          d2s, cand + ((size_t)b * cL + row0) * CPR);
    }
  }
  k_rescore<<<NV / 4, 256, 0, stream>>>(x, cand, nbr);

  hipMemsetAsync(cnt, 0, (size_t)NV * 4, stream);
  hipMemsetAsync(cur, 0, (size_t)NV * 4, stream);
  k_count<<<(NV * cK) / 256, 256, 0, stream>>>(nbr, cnt);
  k_scan<<<cB, 64, 0, stream>>>(cnt, rp);
  k_fill<<<(NV * cK) / 256, 256, 0, stream>>>(nbr, rp, cur, el);

  k_theta1<<<NV * cH / 256, 256, 0, stream>>>(x, w1, b1, g1, be1, h1);
  k_v2e<cH><<<NV / 4, 256, 0, stream>>>(h1, nbr, Y1);
  k_e2v<cH, true><<<NV / 4, 256, 0, stream>>>(Y1, rp, el, h1v);
  k_theta2<<<NV * cC / 256, 256, 0, stream>>>(h1v, w2, b2, g2, be2, h2);
  k_v2e<cC><<<NV / 4, 256, 0, stream>>>(h2, nbr, Y2);
  k_e2v<cC, false><<<NV / 4, 256, 0, stream>>>(Y2, rp, el, out);
}

// Round 5
// 737.690 us; speedup vs baseline: 7.3864x; 1.5540x over previous
//
#include <hip/hip_runtime.h>
#include <math.h>

// HGNNPBlock: per-sample kNN hypergraph (k=30) + 2x (theta -> bn -> v2v mean).
// B=8, L=56*56=3136, C=64, hid=32.
//
// kNN pipeline (R5): MFMA hi/lo-bf16 gram -> u16 fixed-point d2 (full sample,
// 19.7 MB) -> per-row exact top-40 on quantized d2 (register queues) -> fp64
// rescore with rank-by-counting -> exact top-30. Selection error budget:
// quant 0.008 + bf16-split ~0.02 << rank-30..40 d2 gap (~1+); rescore is
// exact over the 40 candidates, so top-30 matches the validated R1 sets.

namespace {

constexpr int cB = 8;
constexpr int cL = 3136;
constexpr int cC = 64;
constexpr int cH = 32;
constexpr int cK = 30;
constexpr int NV = cB * cL;   // 25088
constexpr int CPR = 40;       // candidates per row (margin 10 over k=30)
constexpr float BN_SC = 0.99999500003749964f;  // 1/sqrt(1+1e-5) in fp32

typedef __bf16 bf16x4 __attribute__((ext_vector_type(4)));
typedef __bf16 bf16x8 __attribute__((ext_vector_type(8)));
typedef float floatx4 __attribute__((ext_vector_type(4)));

// ------- K0: split x into bf16 hi/lo + fp32 |x|^2; zero cnt/cur -------
__global__ void k_split(const float* __restrict__ x, ushort* __restrict__ xhi,
                        ushort* __restrict__ xlo, float* __restrict__ sqf,
                        int* __restrict__ cnt, int* __restrict__ cur) {
  int v = blockIdx.x * 256 + threadIdx.x;
  if (v >= NV) return;
  cnt[v] = 0;
  cur[v] = 0;
  const float4* p = reinterpret_cast<const float4*>(x) + (size_t)v * 16;
  double s = 0.0;
#pragma unroll
  for (int c = 0; c < 16; ++c) {
    float4 f = p[c];
    bf16x4 hh, ll;
#pragma unroll
    for (int e = 0; e < 4; ++e) {
      float a = (&f.x)[e];
      __bf16 h = (__bf16)a;
      ll[e] = (__bf16)(a - (float)h);
      hh[e] = h;
      s += (double)a * (double)a;
    }
    *reinterpret_cast<bf16x4*>(&xhi[(size_t)v * 64 + c * 4]) = hh;
    *reinterpret_cast<bf16x4*>(&xlo[(size_t)v * 64 + c * 4]) = ll;
  }
  sqf[v] = (float)s;
}

// ------- K1: MFMA gram -> u16 d2 for one full sample -------
// grid (49, 49); block 256 (4 waves); wave w owns rows w*16..w*16+15.
__global__ __launch_bounds__(256) void k_gemm(const ushort* __restrict__ xhi,
                                              const ushort* __restrict__ xlo,
                                              const float* __restrict__ sqf,
                                              ushort* __restrict__ d2q,
                                              int b) {
  const int jb = blockIdx.y * 64;
  const size_t bbase = (size_t)b * cL;
  const int r0 = blockIdx.x * 64;

  __shared__ ushort aHi[64 * 72], aLo[64 * 72];  // stride 72: conflict-free
  __shared__ ushort bHi[64 * 72], bLo[64 * 72];
  __shared__ float sqJs[64];

  const int t  = threadIdx.x;
  const int ln = t & 63;
  const int w  = t >> 6;
  const int tx = ln & 15;
  const int qd = ln >> 4;

#pragma unroll
  for (int it = 0; it < 2; ++it) {  // 512 row-slots of 8 shorts, 4 arrays
    int idx = t + 256 * it;
    int r = idx >> 3, blk = idx & 7;
    *reinterpret_cast<uint4*>(&aHi[r * 72 + blk * 8]) =
        *reinterpret_cast<const uint4*>(&xhi[(bbase + r0 + r) * 64 + blk * 8]);
    *reinterpret_cast<uint4*>(&aLo[r * 72 + blk * 8]) =
        *reinterpret_cast<const uint4*>(&xlo[(bbase + r0 + r) * 64 + blk * 8]);
    *reinterpret_cast<uint4*>(&bHi[r * 72 + blk * 8]) =
        *reinterpret_cast<const uint4*>(&xhi[(bbase + jb + r) * 64 + blk * 8]);
    *reinterpret_cast<uint4*>(&bLo[r * 72 + blk * 8]) =
        *reinterpret_cast<const uint4*>(&xlo[(bbase + jb + r) * 64 + blk * 8]);
  }
  if (t < 64) sqJs[t] = sqf[bbase + jb + t];
  __syncthreads();

  bf16x8 aH[2], aL[2];
#pragma unroll
  for (int kk = 0; kk < 2; ++kk) {
    aH[kk] = *reinterpret_cast<const bf16x8*>(
        &aHi[(w * 16 + tx) * 72 + kk * 32 + qd * 8]);
    aL[kk] = *reinterpret_cast<const bf16x8*>(
        &aLo[(w * 16 + tx) * 72 + kk * 32 + qd * 8]);
  }

#pragma unroll
  for (int f = 0; f < 4; ++f) {
    const int bro = (f * 16 + tx) * 72 + qd * 8;
    bf16x8 bh0 = *reinterpret_cast<const bf16x8*>(&bHi[bro]);
    bf16x8 bh1 = *reinterpret_cast<const bf16x8*>(&bHi[bro + 32]);
    bf16x8 bl0 = *reinterpret_cast<const bf16x8*>(&bLo[bro]);
    bf16x8 bl1 = *reinterpret_cast<const bf16x8*>(&bLo[bro + 32]);
    floatx4 acc = {0.f, 0.f, 0.f, 0.f};
    acc = __builtin_amdgcn_mfma_f32_16x16x32_bf16(aH[0], bh0, acc, 0, 0, 0);
    acc = __builtin_amdgcn_mfma_f32_16x16x32_bf16(aH[1], bh1, acc, 0, 0, 0);
    acc = __builtin_amdgcn_mfma_f32_16x16x32_bf16(aH[0], bl0, acc, 0, 0, 0);
    acc = __builtin_amdgcn_mfma_f32_16x16x32_bf16(aH[1], bl1, acc, 0, 0, 0);
    acc = __builtin_amdgcn_mfma_f32_16x16x32_bf16(aL[0], bh0, acc, 0, 0, 0);
    acc = __builtin_amdgcn_mfma_f32_16x16x32_bf16(aL[1], bh1, acc, 0, 0, 0);
    const float sj = sqJs[f * 16 + tx];
    const int col = jb + f * 16 + tx;
#pragma unroll
    for (int e = 0; e < 4; ++e) {
      // |xi|^2 dropped (row-constant): within-row ranks unaffected.
      // u16 fixed-point: q = (d2 + 512) * 64, clamped; monotone in d2.
      float qf = fmaf(sj - 2.0f * acc[e], 64.f, 32768.f);
      qf = fminf(fmaxf(qf, 0.f), 65535.f);
      int row = r0 + w * 16 + qd * 4 + e;
      d2q[(size_t)row * cL + col] = (ushort)(unsigned)qf;
    }
  }
}

// ------- K2: per-row exact top-40 on quantized d2 -------
// One wave per row. Lane l scans cols {l+64i}; sorted top-10 register queue of
// packed u32 (q16 << 12 | col). 40 wave-min extractions.
__global__ __launch_bounds__(256) void k_select(const ushort* __restrict__ d2q,
                                                ushort* __restrict__ cand) {
  const int w  = threadIdx.x >> 6;
  const int ln = threadIdx.x & 63;
  const int r  = blockIdx.x * 4 + w;
  const ushort* row = d2q + (size_t)r * cL;

  unsigned q[10];
#pragma unroll
  for (int k = 0; k < 10; ++k) q[k] = 0xFFFFFFFFu;

  for (int i = 0; i < 49; ++i) {  // 3136 = 49*64
    const int col = ln + 64 * i;
    unsigned p = ((unsigned)row[col] << 12) | (unsigned)col;  // 28 bits
    if (p < q[9]) {
      q[9] = p;
#pragma unroll
      for (int k = 9; k > 0; --k) {
        unsigned a = q[k - 1], c = q[k];
        q[k - 1] = min(a, c);
        q[k] = max(a, c);
      }
    }
  }

  ushort* cr = cand + (size_t)r * CPR;
  for (int it = 0; it < CPR; ++it) {
    unsigned h = q[0], m = h;
#pragma unroll
    for (int off = 32; off; off >>= 1)
      m = min(m, (unsigned)__shfl_xor((int)m, off));
    if (ln == 0) cr[it] = (ushort)(m & 0xFFFu);
    if (h == m) {  // unique winner (distinct cols -> distinct packed values)
#pragma unroll
      for (int k = 0; k < 9; ++k) q[k] = q[k + 1];
      q[9] = 0xFFFFFFFFu;
    }
  }
}

// ------- K3: fp64 rescore, rank-by-counting -> exact top-30 + cnt -------
__global__ __launch_bounds__(256) void k_rescore(const float* __restrict__ x,
                                                 const ushort* __restrict__ cand,
                                                 int* __restrict__ nbr,
                                                 int* __restrict__ cnt) {
  const int w  = threadIdx.x >> 6;
  const int ln = threadIdx.x & 63;
  const size_t row = (size_t)blockIdx.x * 4 + w;
  const size_t bvert = row - (row % cL);  // b*cL

  float4 xi[16];
  const float4* xi4 = reinterpret_cast<const float4*>(x + row * 64);
#pragma unroll
  for (int c = 0; c < 16; ++c) xi[c] = xi4[c];

  double dv = 1e300;
  int jv = 0;
  if (ln < CPR) {
    jv = cand[row * CPR + ln];
    const float4* xj4 = reinterpret_cast<const float4*>(x + (bvert + jv) * 64);
    double ax = 0.0, ay = 0.0, az = 0.0, aw = 0.0;  // 4-way ILP
#pragma unroll
    for (int c = 0; c < 16; ++c) {
      float4 xj = xj4[c];
      double d0 = (double)xi[c].x - (double)xj.x; ax = fma(d0, d0, ax);
      double d1 = (double)xi[c].y - (double)xj.y; ay = fma(d1, d1, ay);
      double d2 = (double)xi[c].z - (double)xj.z; az = fma(d2, d2, az);
      double d3 = (double)xi[c].w - (double)xj.w; aw = fma(d3, d3, aw);
    }
    dv = (ax + ay) + (az + aw);
  }

  // rank = #candidates strictly before me in (d, lane) order
  int rank = 0;
  for (int j = 0; j < CPR; ++j) {
    double od = __shfl(dv, j);
    rank += (od < dv || (od == dv && j < ln)) ? 1 : 0;
  }
  if (ln < CPR && rank < cK) {
    nbr[row * cK + rank] = jv;
    atomicAdd(&cnt[bvert + jv], 1);  // fused k_count
  }
}

// ------- CSR: scan + fill (vertex -> edges containing it) -------
__global__ void k_scan(const int* __restrict__ cnt, int* __restrict__ rp) {
  int b = blockIdx.x;
  int ln = threadIdx.x;  // block = 64 = one wave
  const int* c = cnt + b * cL;
  int* r = rp + b * (cL + 1);
  int carry = 0;
  for (int base = 0; base < cL; base += 64) {  // 3136 = 49*64
    int v = c[base + ln];
    int s = v;
#pragma unroll
    for (int off = 1; off < 64; off <<= 1) {
      int u = __shfl_up(s, off);
      if (ln >= off) s += u;
    }
    r[base + ln] = carry + s - v;  // exclusive
    carry += __shfl(s, 63);
  }
  if (ln == 63) r[cL] = carry;
}

__global__ void k_fill(const int* __restrict__ nbr, const int* __restrict__ rp,
                       int* __restrict__ cur, int* __restrict__ el) {
  int g = blockIdx.x * 256 + threadIdx.x;
  if (g >= NV * cK) return;
  int b = g / (cL * cK);
  int e = (g / cK) % cL;
  int v = nbr[g];
  int p = rp[b * (cL + 1) + v] + atomicAdd(&cur[b * cL + v], 1);
  el[(size_t)b * cL * cK + p] = e;
}

// ------- theta1 + bn (eval) -------
__global__ __launch_bounds__(256) void k_theta1(const float* __restrict__ x,
                                                const float* __restrict__ w1,
                                                const float* __restrict__ b1,
                                                const float* __restrict__ g1,
                                                const float* __restrict__ be1,
                                                float* __restrict__ h1) {
  __shared__ float w[cC * cH];
  int t = threadIdx.x;
  for (int n = t; n < cC * cH; n += 256) w[n] = w1[n];
  __syncthreads();
  int g = blockIdx.x * 256 + t;
  int row = g >> 5;
  int f = g & 31;
  const float4* xr = reinterpret_cast<const float4*>(x) + (size_t)row * 16;
  float s = 0.f;
#pragma unroll
  for (int kc = 0; kc < 16; ++kc) {
    float4 xv = xr[kc];
    s += xv.x * w[(4 * kc + 0) * cH + f];
    s += xv.y * w[(4 * kc + 1) * cH + f];
    s += xv.z * w[(4 * kc + 2) * cH + f];
    s += xv.w * w[(4 * kc + 3) * cH + f];
  }
  h1[g] = (s + b1[f]) * (g1[f] * BN_SC) + be1[f];
}

// ------- v2e: mean over k neighbors (wave per edge; indep gathers) -------
template <int F>
__global__ __launch_bounds__(256) void k_v2e(const float* __restrict__ X,
                                             const int* __restrict__ nbr,
                                             float* __restrict__ Y) {
  const int w  = threadIdx.x >> 6;
  const int ln = threadIdx.x & 63;
  const size_t er = (size_t)blockIdx.x * 4 + w;  // b*cL + e
  const size_t b  = er / cL;
  const float* Xb = X + b * cL * F;
  const int* nb = nbr + er * cK;
  const int eidx = nb[ln < cK ? ln : cK - 1];  // one coalesced load
  float s = 0.f;
  if constexpr (F == 64) {
#pragma unroll
    for (int j = 0; j < cK; j += 5) {
      int e0 = __shfl(eidx, j + 0), e1 = __shfl(eidx, j + 1);
      int e2 = __shfl(eidx, j + 2), e3 = __shfl(eidx, j + 3);
      int e4 = __shfl(eidx, j + 4);
      float y0 = Xb[(size_t)e0 * 64 + ln], y1 = Xb[(size_t)e1 * 64 + ln];
      float y2 = Xb[(size_t)e2 * 64 + ln], y3 = Xb[(size_t)e3 * 64 + ln];
      float y4 = Xb[(size_t)e4 * 64 + ln];
      s += ((y0 + y1) + (y2 + y3)) + y4;
    }
    Y[er * 64 + ln] = s * (1.f / 30.f);
  } else {  // F == 32: both half-waves work, 2 neighbors per step
    const int hi = ln >> 5, f = ln & 31;
#pragma unroll
    for (int j = 0; j < cK; j += 6) {
      int e0 = __shfl(eidx, j + 0 + hi);
      int e1 = __shfl(eidx, j + 2 + hi);
      int e2 = __shfl(eidx, j + 4 + hi);
      float y0 = Xb[(size_t)e0 * 32 + f], y1 = Xb[(size_t)e1 * 32 + f];
      float y2 = Xb[(size_t)e2 * 32 + f];
      s += (y0 + y1) + y2;
    }
    s += __shfl_xor(s, 32);
    if (hi == 0) Y[er * 32 + f] = s * (1.f / 30.f);
  }
}

// ------- e2v(F=32) + relu + theta2 + bn fused (wave per vertex) -------
__global__ __launch_bounds__(256) void k_e2v_t2(const float* __restrict__ Y,
                                                const int* __restrict__ rp,
                                                const int* __restrict__ el,
                                                const float* __restrict__ w2,
                                                const float* __restrict__ b2,
                                                const float* __restrict__ g2,
                                                const float* __restrict__ be2,
                                                float* __restrict__ h2) {
  __shared__ float w2s[cH * cC];  // 8 KB
  {
    int t = threadIdx.x;
    for (int n = t; n < cH * cC; n += 256) w2s[n] = w2[n];
  }
  const int w  = threadIdx.x >> 6;
  const int ln = threadIdx.x & 63;
  const size_t vr = (size_t)blockIdx.x * 4 + w;  // b*cL + v
  const size_t b  = vr / cL;
  const int v = (int)(vr % cL);
  const int* rpb = rp + b * (cL + 1);
  const int s0 = rpb[v];
  const int deg = rpb[v + 1] - s0;  // >= 1 (self edge always selected)
  const int* elb = el + b * (size_t)cL * cK + s0;
  const float* Yb = Y + b * cL * cH;
  const int hi = ln >> 5, f = ln & 31;
  float s = 0.f;

  for (int base = 0; base < deg; base += 64) {
    const int take = min(64, deg - base);
    const int eidx = elb[base + (ln < take ? ln : 0)];  // parallel load
    int j = 0;
    for (; j + 4 <= take; j += 4) {
      int e0 = __shfl(eidx, j + 0 + hi);
      int e1 = __shfl(eidx, j + 2 + hi);
      s += Yb[(size_t)e0 * 32 + f] + Yb[(size_t)e1 * 32 + f];
    }
    for (; j < take; j += 2) {
      int jj = j + hi;
      int e0 = __shfl(eidx, jj < take ? jj : 0);
      float y = Yb[(size_t)e0 * 32 + f];
      s += (jj < take) ? y : 0.f;
    }
  }
  __syncthreads();  // w2s ready (also covers gather loads' wave divergence)

  s += __shfl_xor(s, 32);
  float r = fmaxf(s / (float)deg, 0.f);  // e2v mean + relu; all lanes: r(f)

  // theta2: out[ln] = sum_k r_k * w2[k][ln]; r_k broadcast from lane k
  float s2 = 0.f;
#pragma unroll 8
  for (int k = 0; k < cH; ++k) {
    float rk = __shfl(r, k);
    s2 = fmaf(rk, w2s[k * cC + ln], s2);
  }
  h2[vr * 64 + ln] = (s2 + b2[ln]) * (g2[ln] * BN_SC) + be2[ln];
}

// ------- final e2v (F=64, no relu) -------
__global__ __launch_bounds__(256) void k_e2v64(const float* __restrict__ Y,
                                               const int* __restrict__ rp,
                                               const int* __restrict__ el,
                                               float* __restrict__ out) {
  const int w  = threadIdx.x >> 6;
  const int ln = threadIdx.x & 63;
  const size_t vr = (size_t)blockIdx.x * 4 + w;  // b*cL + v
  const size_t b  = vr / cL;
  const int v = (int)(vr % cL);
  const int* rpb = rp + b * (cL + 1);
  const int s0 = rpb[v];
  const int deg = rpb[v + 1] - s0;
  const int* elb = el + b * (size_t)cL * cK + s0;
  const float* Yb = Y + b * cL * 64;
  float s = 0.f;

  for (int base = 0; base < deg; base += 64) {
    const int take = min(64, deg - base);
    const int eidx = elb[base + (ln < take ? ln : 0)];
    int j = 0;
    for (; j + 4 <= take; j += 4) {
      int e0 = __shfl(eidx, j + 0), e1 = __shfl(eidx, j + 1);
      int e2 = __shfl(eidx, j + 2), e3 = __shfl(eidx, j + 3);
      float y0 = Yb[(size_t)e0 * 64 + ln], y1 = Yb[(size_t)e1 * 64 + ln];
      float y2 = Yb[(size_t)e2 * 64 + ln], y3 = Yb[(size_t)e3 * 64 + ln];
      s += (y0 + y1) + (y2 + y3);
    }
    for (; j < take; ++j) s += Yb[(size_t)__shfl(eidx, j) * 64 + ln];
  }
  out[vr * 64 + ln] = s / (float)deg;
}

}  // namespace

extern "C" void kernel_launch(void* const* d_in, const int* in_sizes, int n_in,
                              void* d_out, int out_size, void* d_ws,
                              size_t ws_size, hipStream_t stream) {
  (void)in_sizes; (void)n_in; (void)out_size; (void)ws_size;
  const float* x   = (const float*)d_in[0];
  const float* w1  = (const float*)d_in[1];
  const float* b1  = (const float*)d_in[2];
  const float* g1  = (const float*)d_in[3];
  const float* be1 = (const float*)d_in[4];
  const float* w2  = (const float*)d_in[5];
  const float* b2  = (const float*)d_in[6];
  const float* g2  = (const float*)d_in[7];
  const float* be2 = (const float*)d_in[8];
  float* out = (float*)d_out;

  // workspace: ~31.5 MB peak (<= R3/R4's proven 31.7 MB)
  char* base = (char*)d_ws;
  size_t off = 0;
  auto carve = [&](size_t bytes) {
    char* p = base + off;
    off += (bytes + 255) & ~(size_t)255;
    return p;
  };
  float*  sqf  = (float*)carve((size_t)NV * 4);
  int*    nbr  = (int*)carve((size_t)NV * cK * 4);
  int*    rp   = (int*)carve((size_t)cB * (cL + 1) * 4);
  ushort* cand = (ushort*)carve((size_t)NV * CPR * 2);
  int*    cnt  = (int*)carve((size_t)NV * 4);  // dedicated (zeroed in split)
  int*    cur  = (int*)carve((size_t)NV * 4);
  // region A: {xhi|xlo} (dead after last k_gemm) then {el}
  char* RA = carve((size_t)NV * 64 * 2 * 2);  // 6,422,528
  ushort* xhi = (ushort*)RA;
  ushort* xlo = (ushort*)(RA + 3211264);
  int* el  = (int*)RA;
  // region B: u16 d2 (one sample, dead after last select) then activations
  char* RB = carve((size_t)cL * cL * 2);  // 19,668,992
  ushort* d2q = (ushort*)RB;
  float* h1 = (float*)RB;                  // 3.2 MB
  float* Y1 = (float*)(RB + 3211264);      // 3.2 MB
  float* h2 = (float*)(RB + 6422528);      // 6.4 MB
  float* Y2 = (float*)RB;                  // 6.4 MB (h1/Y1 dead by then)

  k_split<<<(NV + 255) / 256, 256, 0, stream>>>(x, xhi, xlo, sqf, cnt, cur);

  for (int b = 0; b < cB; ++b) {
    k_gemm<<<dim3(49, 49), 256, 0, stream>>>(xhi, xlo, sqf, d2q, b);
    k_select<<<cL / 4, 256, 0, stream>>>(d2q, cand + (size_t)b * cL * CPR);
  }
  k_rescore<<<NV / 4, 256, 0, stream>>>(x, cand, nbr, cnt);

  k_scan<<<cB, 64, 0, stream>>>(cnt, rp);
  k_fill<<<(NV * cK) / 256, 256, 0, stream>>>(nbr, rp, cur, el);

  k_theta1<<<NV * cH / 256, 256, 0, stream>>>(x, w1, b1, g1, be1, h1);
  k_v2e<cH><<<NV / 4, 256, 0, stream>>>(h1, nbr, Y1);
  k_e2v_t2<<<NV / 4, 256, 0, stream>>>(Y1, rp, el, w2, b2, g2, be2, h2);
  k_v2e<cC><<<NV / 4, 256, 0, stream>>>(h2, nbr, Y2);
  k_e2v64<<<NV / 4, 256, 0, stream>>>(Y2, rp, el, out);
}

// Round 6
// 548.080 us; speedup vs baseline: 9.9417x; 1.3460x over previous
//
#include <hip/hip_runtime.h>
#include <math.h>

// HGNNPBlock: per-sample kNN hypergraph (k=30) + 2x (theta -> bn -> v2v mean).
// B=8, L=56*56=3136, C=64, hid=32.
//
// R6 kNN: single fused sweep kernel -- MFMA hi/lo-bf16 gram tiles + per-lane
// sorted top-14 register queues (no d2 materialization, no LDS heaps) ->
// per-half sorted top-40 (u32 packed q16|col12). Rescore merges halves via
// the bitonic-split identity min(A[i],B[39-i]) and does the exact fp64
// re-rank ONLY when the quantized 29/30 boundary gap <= 3 units (nbr is a
// SET -- v2v is a mean -- so unambiguous rows need no rescoring).

namespace {

constexpr int cB = 8;
constexpr int cL = 3136;
constexpr int cC = 64;
constexpr int cH = 32;
constexpr int cK = 30;
constexpr int NV = cB * cL;   // 25088
constexpr float BN_SC = 0.99999500003749964f;  // 1/sqrt(1+1e-5) in fp32

typedef __bf16 bf16x4 __attribute__((ext_vector_type(4)));
typedef __bf16 bf16x8 __attribute__((ext_vector_type(8)));
typedef float floatx4 __attribute__((ext_vector_type(4)));

__device__ inline unsigned umin2(unsigned a, unsigned b) { return a < b ? a : b; }
__device__ inline unsigned umax2(unsigned a, unsigned b) { return a > b ? a : b; }

// ------- K0: split x into bf16 hi/lo + fp32 |x|^2; zero cnt/cur -------
__global__ void k_split(const float* __restrict__ x, ushort* __restrict__ xhi,
                        ushort* __restrict__ xlo, float* __restrict__ sqf,
                        int* __restrict__ cnt, int* __restrict__ cur) {
  int v = blockIdx.x * 256 + threadIdx.x;
  if (v >= NV) return;
  cnt[v] = 0;
  cur[v] = 0;
  const float4* p = reinterpret_cast<const float4*>(x) + (size_t)v * 16;
  double s = 0.0;
#pragma unroll
  for (int c = 0; c < 16; ++c) {
    float4 f = p[c];
    bf16x4 hh, ll;
#pragma unroll
    for (int e = 0; e < 4; ++e) {
      float a = (&f.x)[e];
      __bf16 h = (__bf16)a;
      ll[e] = (__bf16)(a - (float)h);
      hh[e] = h;
      s += (double)a * (double)a;
    }
    *reinterpret_cast<bf16x4*>(&xhi[(size_t)v * 64 + c * 4]) = hh;
    *reinterpret_cast<bf16x4*>(&xlo[(size_t)v * 64 + c * 4]) = ll;
  }
  sqf[v] = (float)s;
}

// ------- K1: fused gram sweep + per-lane top-14 queues -> per-half top-40 ---
// grid (49, 2, 8): 64-row strip x col-half x sample. block 256 (4 waves);
// wave w rows w*16..w*16+15; lane (tx,qd) owns rows qd*4+e, cols f*16+tx.
// Queue safety: >14 of a half's top-40 in one lane's ~100-col class:
// Poisson(2.5) tail ~7e-8 -> ~0.06 expected misses chip-wide.
__global__ __launch_bounds__(256, 3) void k_sweep(
    const ushort* __restrict__ xhi, const ushort* __restrict__ xlo,
    const float* __restrict__ sqf, unsigned* __restrict__ candq) {
  const int ib = blockIdx.x, half = blockIdx.y, b = blockIdx.z;
  const int r0 = ib * 64;
  const int jb0 = half ? 1600 : 0;
  const int ntile = half ? 24 : 25;
  const size_t bbase = (size_t)b * cL;

  __shared__ ushort aHi[64 * 72], aLo[64 * 72];  // stride 72: conflict-free
  __shared__ ushort bHi[64 * 72], bLo[64 * 72];
  __shared__ float sqJs[64];

  const int t  = threadIdx.x;
  const int ln = t & 63;
  const int w  = t >> 6;
  const int tx = ln & 15;
  const int qd = ln >> 4;

#pragma unroll
  for (int it = 0; it < 2; ++it) {  // stage A strip once (hi+lo)
    int idx = t + 256 * it;
    int r = idx >> 3, blk = idx & 7;
    *reinterpret_cast<uint4*>(&aHi[r * 72 + blk * 8]) =
        *reinterpret_cast<const uint4*>(&xhi[(bbase + r0 + r) * 64 + blk * 8]);
    *reinterpret_cast<uint4*>(&aLo[r * 72 + blk * 8]) =
        *reinterpret_cast<const uint4*>(&xlo[(bbase + r0 + r) * 64 + blk * 8]);
  }
  __syncthreads();

  bf16x8 aH[2], aL[2];
#pragma unroll
  for (int kk = 0; kk < 2; ++kk) {
    aH[kk] = *reinterpret_cast<const bf16x8*>(
        &aHi[(w * 16 + tx) * 72 + kk * 32 + qd * 8]);
    aL[kk] = *reinterpret_cast<const bf16x8*>(
        &aLo[(w * 16 + tx) * 72 + kk * 32 + qd * 8]);
  }

  unsigned q[4][14];  // per-row sorted top-14 (ascending), packed q16|col12
#pragma unroll
  for (int e = 0; e < 4; ++e)
#pragma unroll
    for (int k = 0; k < 14; ++k) q[e][k] = 0xFFFFFFFFu;

  for (int st = 0; st < ntile; ++st) {
    const int jb = jb0 + st * 64;
#pragma unroll
    for (int it = 0; it < 2; ++it) {  // stage B tile
      int idx = t + 256 * it;
      int r = idx >> 3, blk = idx & 7;
      *reinterpret_cast<uint4*>(&bHi[r * 72 + blk * 8]) =
          *reinterpret_cast<const uint4*>(&xhi[(bbase + jb + r) * 64 + blk * 8]);
      *reinterpret_cast<uint4*>(&bLo[r * 72 + blk * 8]) =
          *reinterpret_cast<const uint4*>(&xlo[(bbase + jb + r) * 64 + blk * 8]);
    }
    if (t < 64) sqJs[t] = sqf[bbase + jb + t];
    __syncthreads();

    float d2v[4][4];
#pragma unroll
    for (int f = 0; f < 4; ++f) {
      const int bro = (f * 16 + tx) * 72 + qd * 8;
      bf16x8 bh0 = *reinterpret_cast<const bf16x8*>(&bHi[bro]);
      bf16x8 bh1 = *reinterpret_cast<const bf16x8*>(&bHi[bro + 32]);
      bf16x8 bl0 = *reinterpret_cast<const bf16x8*>(&bLo[bro]);
      bf16x8 bl1 = *reinterpret_cast<const bf16x8*>(&bLo[bro + 32]);
      floatx4 acc = {0.f, 0.f, 0.f, 0.f};
      acc = __builtin_amdgcn_mfma_f32_16x16x32_bf16(aH[0], bh0, acc, 0, 0, 0);
      acc = __builtin_amdgcn_mfma_f32_16x16x32_bf16(aH[1], bh1, acc, 0, 0, 0);
      acc = __builtin_amdgcn_mfma_f32_16x16x32_bf16(aH[0], bl0, acc, 0, 0, 0);
      acc = __builtin_amdgcn_mfma_f32_16x16x32_bf16(aH[1], bl1, acc, 0, 0, 0);
      acc = __builtin_amdgcn_mfma_f32_16x16x32_bf16(aL[0], bh0, acc, 0, 0, 0);
      acc = __builtin_amdgcn_mfma_f32_16x16x32_bf16(aL[1], bh1, acc, 0, 0, 0);
      const float sj = sqJs[f * 16 + tx];
#pragma unroll
      for (int e = 0; e < 4; ++e) d2v[f][e] = sj - 2.0f * acc[e];
    }

    // selection: u16 fixed-point q=(d2+512)*64 (monotone), predicated bubbles
#pragma unroll
    for (int e = 0; e < 4; ++e) {
#pragma unroll
      for (int f = 0; f < 4; ++f) {
        float qf = fmaf(d2v[f][e], 64.f, 32768.f);
        qf = fminf(fmaxf(qf, 0.f), 65535.f);
        unsigned p = ((unsigned)qf << 12) | (unsigned)(jb + f * 16 + tx);
        if (p < q[e][13]) {
          q[e][13] = p;
#pragma unroll
          for (int k = 13; k > 0; --k) {
            unsigned a = q[e][k - 1], c = q[e][k];
            q[e][k - 1] = umin2(a, c);
            q[e][k] = umax2(a, c);
          }
        }
      }
    }
    __syncthreads();  // protect B tiles before next staging
  }

  // extraction: per row, 40 wave-min steps over the 16 tx-lane queue heads
  // (shfl_xor masks <16 stay within the qd group) -> sorted top-40 emit
#pragma unroll
  for (int e = 0; e < 4; ++e) {
    const size_t rowG = bbase + r0 + w * 16 + qd * 4 + e;
    unsigned* cr = candq + rowG * 80 + half * 40;
    for (int it = 0; it < 40; ++it) {
      unsigned h = q[e][0];
      unsigned m = h;
      m = umin2(m, (unsigned)__shfl_xor((int)m, 1));
      m = umin2(m, (unsigned)__shfl_xor((int)m, 2));
      m = umin2(m, (unsigned)__shfl_xor((int)m, 4));
      m = umin2(m, (unsigned)__shfl_xor((int)m, 8));
      if (tx == 0) cr[it] = m;
      if (h == m) {  // unique (distinct cols) -> exactly one lane pops
#pragma unroll
        for (int k = 0; k < 13; ++k) q[e][k] = q[e][k + 1];
        q[e][13] = 0xFFFFFFFFu;
      }
    }
  }
}

// ------- K2: merge halves + conditional exact fp64 re-rank -> top-30 -------
__global__ __launch_bounds__(256) void k_rescore(const float* __restrict__ x,
                                                 const unsigned* __restrict__ candq,
                                                 int* __restrict__ nbr,
                                                 int* __restrict__ cnt) {
  const int w  = threadIdx.x >> 6;
  const int ln = threadIdx.x & 63;
  const size_t row = (size_t)blockIdx.x * 4 + w;
  const size_t bvert = row - (row % cL);  // b*cL

  const unsigned* cq = candq + row * 80;
  unsigned A  = (ln < 40) ? cq[ln] : 0xFFFFFFFFu;
  unsigned Bv = (ln < 40) ? cq[40 + ln] : 0xFFFFFFFFu;
  unsigned Br = (unsigned)__shfl((int)Bv, (39 - ln) & 63);
  unsigned m  = (ln < 40) ? umin2(A, Br) : 0xFFFFFFFFu;  // bitonic-split merge

  int rank = 0;  // rank among the merged 40 (values unique: distinct cols)
  for (int j = 0; j < 40; ++j) {
    unsigned om = (unsigned)__shfl((int)m, j);
    rank += (om < m) ? 1 : 0;
  }
  const unsigned qv = m >> 12;
  const int col = (int)(m & 0xFFFu);

  // boundary gap between quantized rank-29 and rank-30 values
  unsigned lowmax = (rank < 30) ? qv : 0u;
  unsigned upmin  = (rank >= 30 && ln < 40) ? qv : 0xFFFFFu;
#pragma unroll
  for (int off = 32; off; off >>= 1) {
    lowmax = umax2(lowmax, (unsigned)__shfl_xor((int)lowmax, off));
    upmin  = umin2(upmin,  (unsigned)__shfl_xor((int)upmin,  off));
  }
  // error budget: 1 unit quant truncation + ~0.1 unit bf16-split; 3 = 2x margin
  if (upmin > lowmax + 3) {
    if (rank < cK) {
      nbr[row * cK + rank] = col;
      atomicAdd(&cnt[bvert + col], 1);
    }
    return;
  }

  // ambiguous boundary: exact fp64 re-rank of the 40 merged candidates
  float4 xi[16];
  const float4* xi4 = reinterpret_cast<const float4*>(x + row * 64);
#pragma unroll
  for (int c = 0; c < 16; ++c) xi[c] = xi4[c];

  double dv = 1e300;
  if (ln < 40) {
    const float4* xj4 = reinterpret_cast<const float4*>(x + (bvert + col) * 64);
    double ax = 0.0, ay = 0.0, az = 0.0, aw = 0.0;
#pragma unroll
    for (int c = 0; c < 16; ++c) {
      float4 xj = xj4[c];
      double d0 = (double)xi[c].x - (double)xj.x; ax = fma(d0, d0, ax);
      double d1 = (double)xi[c].y - (double)xj.y; ay = fma(d1, d1, ay);
      double d2 = (double)xi[c].z - (double)xj.z; az = fma(d2, d2, az);
      double d3 = (double)xi[c].w - (double)xj.w; aw = fma(d3, d3, aw);
    }
    dv = (ax + ay) + (az + aw);
  }
  int r2 = 0;
  for (int j = 0; j < 40; ++j) {
    double od = __shfl(dv, j);
    r2 += (od < dv || (od == dv && j < ln)) ? 1 : 0;
  }
  if (ln < 40 && r2 < cK) {
    nbr[row * cK + r2] = col;
    atomicAdd(&cnt[bvert + col], 1);
  }
}

// ------- CSR: scan + fill (vertex -> edges containing it) -------
__global__ void k_scan(const int* __restrict__ cnt, int* __restrict__ rp) {
  int b = blockIdx.x;
  int ln = threadIdx.x;  // block = 64 = one wave
  const int* c = cnt + b * cL;
  int* r = rp + b * (cL + 1);
  int carry = 0;
  for (int base = 0; base < cL; base += 64) {  // 3136 = 49*64
    int v = c[base + ln];
    int s = v;
#pragma unroll
    for (int off = 1; off < 64; off <<= 1) {
      int u = __shfl_up(s, off);
      if (ln >= off) s += u;
    }
    r[base + ln] = carry + s - v;  // exclusive
    carry += __shfl(s, 63);
  }
  if (ln == 63) r[cL] = carry;
}

__global__ void k_fill(const int* __restrict__ nbr, const int* __restrict__ rp,
                       int* __restrict__ cur, int* __restrict__ el) {
  int g = blockIdx.x * 256 + threadIdx.x;
  if (g >= NV * cK) return;
  int b = g / (cL * cK);
  int e = (g / cK) % cL;
  int v = nbr[g];
  int p = rp[b * (cL + 1) + v] + atomicAdd(&cur[b * cL + v], 1);
  el[(size_t)b * cL * cK + p] = e;
}

// ------- theta1 + bn (eval) -------
__global__ __launch_bounds__(256) void k_theta1(const float* __restrict__ x,
                                                const float* __restrict__ w1,
                                                const float* __restrict__ b1,
                                                const float* __restrict__ g1,
                                                const float* __restrict__ be1,
                                                float* __restrict__ h1) {
  __shared__ float w[cC * cH];
  int t = threadIdx.x;
  for (int n = t; n < cC * cH; n += 256) w[n] = w1[n];
  __syncthreads();
  int g = blockIdx.x * 256 + t;
  int row = g >> 5;
  int f = g & 31;
  const float4* xr = reinterpret_cast<const float4*>(x) + (size_t)row * 16;
  float s = 0.f;
#pragma unroll
  for (int kc = 0; kc < 16; ++kc) {
    float4 xv = xr[kc];
    s += xv.x * w[(4 * kc + 0) * cH + f];
    s += xv.y * w[(4 * kc + 1) * cH + f];
    s += xv.z * w[(4 * kc + 2) * cH + f];
    s += xv.w * w[(4 * kc + 3) * cH + f];
  }
  h1[g] = (s + b1[f]) * (g1[f] * BN_SC) + be1[f];
}

// ------- v2e: mean over k neighbors (wave per edge; indep gathers) -------
template <int F>
__global__ __launch_bounds__(256) void k_v2e(const float* __restrict__ X,
                                             const int* __restrict__ nbr,
                                             float* __restrict__ Y) {
  const int w  = threadIdx.x >> 6;
  const int ln = threadIdx.x & 63;
  const size_t er = (size_t)blockIdx.x * 4 + w;  // b*cL + e
  const size_t b  = er / cL;
  const float* Xb = X + b * cL * F;
  const int* nb = nbr + er * cK;
  const int eidx = nb[ln < cK ? ln : cK - 1];  // one coalesced load
  float s = 0.f;
  if constexpr (F == 64) {
#pragma unroll
    for (int j = 0; j < cK; j += 5) {
      int e0 = __shfl(eidx, j + 0), e1 = __shfl(eidx, j + 1);
      int e2 = __shfl(eidx, j + 2), e3 = __shfl(eidx, j + 3);
      int e4 = __shfl(eidx, j + 4);
      float y0 = Xb[(size_t)e0 * 64 + ln], y1 = Xb[(size_t)e1 * 64 + ln];
      float y2 = Xb[(size_t)e2 * 64 + ln], y3 = Xb[(size_t)e3 * 64 + ln];
      float y4 = Xb[(size_t)e4 * 64 + ln];
      s += ((y0 + y1) + (y2 + y3)) + y4;
    }
    Y[er * 64 + ln] = s * (1.f / 30.f);
  } else {  // F == 32: both half-waves work, 2 neighbors per step
    const int hi = ln >> 5, f = ln & 31;
#pragma unroll
    for (int j = 0; j < cK; j += 6) {
      int e0 = __shfl(eidx, j + 0 + hi);
      int e1 = __shfl(eidx, j + 2 + hi);
      int e2 = __shfl(eidx, j + 4 + hi);
      float y0 = Xb[(size_t)e0 * 32 + f], y1 = Xb[(size_t)e1 * 32 + f];
      float y2 = Xb[(size_t)e2 * 32 + f];
      s += (y0 + y1) + y2;
    }
    s += __shfl_xor(s, 32);
    if (hi == 0) Y[er * 32 + f] = s * (1.f / 30.f);
  }
}

// ------- e2v(F=32) + relu + theta2 + bn fused (wave per vertex) -------
__global__ __launch_bounds__(256) void k_e2v_t2(const float* __restrict__ Y,
                                                const int* __restrict__ rp,
                                                const int* __restrict__ el,
                                                const float* __restrict__ w2,
                                                const float* __restrict__ b2,
                                                const float* __restrict__ g2,
                                                const float* __restrict__ be2,
                                                float* __restrict__ h2) {
  __shared__ float w2s[cH * cC];  // 8 KB
  {
    int t = threadIdx.x;
    for (int n = t; n < cH * cC; n += 256) w2s[n] = w2[n];
  }
  const int w  = threadIdx.x >> 6;
  const int ln = threadIdx.x & 63;
  const size_t vr = (size_t)blockIdx.x * 4 + w;  // b*cL + v
  const size_t b  = vr / cL;
  const int v = (int)(vr % cL);
  const int* rpb = rp + b * (cL + 1);
  const int s0 = rpb[v];
  const int deg = rpb[v + 1] - s0;  // >= 1 (self edge always selected)
  const int* elb = el + b * (size_t)cL * cK + s0;
  const float* Yb = Y + b * cL * cH;
  const int hi = ln >> 5, f = ln & 31;
  float s = 0.f;

  for (int base = 0; base < deg; base += 64) {
    const int take = min(64, deg - base);
    const int eidx = elb[base + (ln < take ? ln : 0)];  // parallel load
    int j = 0;
    for (; j + 4 <= take; j += 4) {
      int e0 = __shfl(eidx, j + 0 + hi);
      int e1 = __shfl(eidx, j + 2 + hi);
      s += Yb[(size_t)e0 * 32 + f] + Yb[(size_t)e1 * 32 + f];
    }
    for (; j < take; j += 2) {
      int jj = j + hi;
      int e0 = __shfl(eidx, jj < take ? jj : 0);
      float y = Yb[(size_t)e0 * 32 + f];
      s += (jj < take) ? y : 0.f;
    }
  }
  __syncthreads();  // w2s ready

  s += __shfl_xor(s, 32);
  float r = fmaxf(s / (float)deg, 0.f);  // e2v mean + relu

  // theta2: out[ln] = sum_k r_k * w2[k][ln]; r_k broadcast from lane k
  float s2 = 0.f;
#pragma unroll 8
  for (int k = 0; k < cH; ++k) {
    float rk = __shfl(r, k);
    s2 = fmaf(rk, w2s[k * cC + ln], s2);
  }
  h2[vr * 64 + ln] = (s2 + b2[ln]) * (g2[ln] * BN_SC) + be2[ln];
}

// ------- final e2v (F=64, no relu) -------
__global__ __launch_bounds__(256) void k_e2v64(const float* __restrict__ Y,
                                               const int* __restrict__ rp,
                                               const int* __restrict__ el,
                                               float* __restrict__ out) {
  const int w  = threadIdx.x >> 6;
  const int ln = threadIdx.x & 63;
  const size_t vr = (size_t)blockIdx.x * 4 + w;  // b*cL + v
  const size_t b  = vr / cL;
  const int v = (int)(vr % cL);
  const int* rpb = rp + b * (cL + 1);
  const int s0 = rpb[v];
  const int deg = rpb[v + 1] - s0;
  const int* elb = el + b * (size_t)cL * cK + s0;
  const float* Yb = Y + b * cL * 64;
  float s = 0.f;

  for (int base = 0; base < deg; base += 64) {
    const int take = min(64, deg - base);
    const int eidx = elb[base + (ln < take ? ln : 0)];
    int j = 0;
    for (; j + 4 <= take; j += 4) {
      int e0 = __shfl(eidx, j + 0), e1 = __shfl(eidx, j + 1);
      int e2 = __shfl(eidx, j + 2), e3 = __shfl(eidx, j + 3);
      float y0 = Yb[(size_t)e0 * 64 + ln], y1 = Yb[(size_t)e1 * 64 + ln];
      float y2 = Yb[(size_t)e2 * 64 + ln], y3 = Yb[(size_t)e3 * 64 + ln];
      s += (y0 + y1) + (y2 + y3);
    }
    for (; j < take; ++j) s += Yb[(size_t)__shfl(eidx, j) * 64 + ln];
  }
  out[vr * 64 + ln] = s / (float)deg;
}

}  // namespace

extern "C" void kernel_launch(void* const* d_in, const int* in_sizes, int n_in,
                              void* d_out, int out_size, void* d_ws,
                              size_t ws_size, hipStream_t stream) {
  (void)in_sizes; (void)n_in; (void)out_size; (void)ws_size;
  const float* x   = (const float*)d_in[0];
  const float* w1  = (const float*)d_in[1];
  const float* b1  = (const float*)d_in[2];
  const float* g1  = (const float*)d_in[3];
  const float* be1 = (const float*)d_in[4];
  const float* w2  = (const float*)d_in[5];
  const float* b2  = (const float*)d_in[6];
  const float* g2  = (const float*)d_in[7];
  const float* be2 = (const float*)d_in[8];
  float* out = (float*)d_out;

  // workspace: ~24.3 MB peak (<= R5's proven ~31.5 MB)
  char* base = (char*)d_ws;
  size_t off = 0;
  auto carve = [&](size_t bytes) {
    char* p = base + off;
    off += (bytes + 255) & ~(size_t)255;
    return p;
  };
  float* sqf = (float*)carve((size_t)NV * 4);
  int*   nbr = (int*)carve((size_t)NV * cK * 4);
  int*   rp  = (int*)carve((size_t)cB * (cL + 1) * 4);
  int*   cnt = (int*)carve((size_t)NV * 4);
  int*   cur = (int*)carve((size_t)NV * 4);
  // region A: {xhi|xlo} (dead after k_sweep) then {el}
  char* RA = carve((size_t)NV * 64 * 2 * 2);  // 6,422,528
  ushort* xhi = (ushort*)RA;
  ushort* xlo = (ushort*)(RA + 3211264);
  int* el = (int*)RA;
  // region C: candq (8 MB, dead after rescore) then h1+Y1, later Y2
  char* RC = carve((size_t)NV * 80 * 4);  // 8,028,160
  unsigned* candq = (unsigned*)RC;
  float* h1 = (float*)RC;                 // 3.2 MB
  float* Y1 = (float*)(RC + 3211264);     // 3.2 MB
  float* Y2 = (float*)RC;                 // 6.4 MB (h1/Y1 dead by then)
  // region D: h2 (6.4 MB)
  float* h2 = (float*)carve((size_t)NV * cC * 4);

  k_split<<<(NV + 255) / 256, 256, 0, stream>>>(x, xhi, xlo, sqf, cnt, cur);
  k_sweep<<<dim3(49, 2, cB), 256, 0, stream>>>(xhi, xlo, sqf, candq);
  k_rescore<<<NV / 4, 256, 0, stream>>>(x, candq, nbr, cnt);

  k_scan<<<cB, 64, 0, stream>>>(cnt, rp);
  k_fill<<<(NV * cK) / 256, 256, 0, stream>>>(nbr, rp, cur, el);

  k_theta1<<<NV * cH / 256, 256, 0, stream>>>(x, w1, b1, g1, be1, h1);
  k_v2e<cH><<<NV / 4, 256, 0, stream>>>(h1, nbr, Y1);
  k_e2v_t2<<<NV / 4, 256, 0, stream>>>(Y1, rp, el, w2, b2, g2, be2, h2);
  k_v2e<cC><<<NV / 4, 256, 0, stream>>>(h2, nbr, Y2);
  k_e2v64<<<NV / 4, 256, 0, stream>>>(Y2, rp, el, out);
}

// Round 7
// 507.449 us; speedup vs baseline: 10.7378x; 1.0801x over previous
//
#include <hip/hip_runtime.h>
#include <math.h>

// HGNNPBlock: per-sample kNN hypergraph (k=30) + 2x (theta -> bn -> v2v mean).
// B=8, L=56*56=3136, C=64, hid=32.
//
// R7: sweep split into column QUARTERS (grid 1568: R6's 784 blocks = 3 blk/CU
// starved latency hiding -> Occ 21%) + float-threshold gate on the selection
// common path. Rescore merges 4 sorted top-40 lists with shfl-only bitonic
// networks. Activations in bf16 (halves gather traffic); gather kernels issue
// all loads independently (latency-bound lesson from R3/R4).

namespace {

constexpr int cB = 8;
constexpr int cL = 3136;
constexpr int cC = 64;
constexpr int cH = 32;
constexpr int cK = 30;
constexpr int NV = cB * cL;   // 25088
constexpr float BN_SC = 0.99999500003749964f;  // 1/sqrt(1+1e-5) in fp32

typedef __bf16 bf16x4 __attribute__((ext_vector_type(4)));
typedef __bf16 bf16x8 __attribute__((ext_vector_type(8)));
typedef float floatx4 __attribute__((ext_vector_type(4)));

__device__ inline unsigned umin2(unsigned a, unsigned b) { return a < b ? a : b; }
__device__ inline unsigned umax2(unsigned a, unsigned b) { return a > b ? a : b; }

// sort a bitonic 64-sequence (one value per lane) ascending, shfl-only
__device__ inline unsigned bclean64(unsigned v, int ln) {
#pragma unroll
  for (int off = 32; off; off >>= 1) {
    unsigned p = (unsigned)__shfl_xor((int)v, off);
    v = (ln & off) ? umax2(v, p) : umin2(v, p);
  }
  return v;
}

// ------- K0: split x into bf16 hi/lo + fp32 |x|^2; zero cnt/cur -------
__global__ void k_split(const float* __restrict__ x, ushort* __restrict__ xhi,
                        ushort* __restrict__ xlo, float* __restrict__ sqf,
                        int* __restrict__ cnt, int* __restrict__ cur) {
  int v = blockIdx.x * 256 + threadIdx.x;
  if (v >= NV) return;
  cnt[v] = 0;
  cur[v] = 0;
  const float4* p = reinterpret_cast<const float4*>(x) + (size_t)v * 16;
  double s = 0.0;
#pragma unroll
  for (int c = 0; c < 16; ++c) {
    float4 f = p[c];
    bf16x4 hh, ll;
#pragma unroll
    for (int e = 0; e < 4; ++e) {
      float a = (&f.x)[e];
      __bf16 h = (__bf16)a;
      ll[e] = (__bf16)(a - (float)h);
      hh[e] = h;
      s += (double)a * (double)a;
    }
    *reinterpret_cast<bf16x4*>(&xhi[(size_t)v * 64 + c * 4]) = hh;
    *reinterpret_cast<bf16x4*>(&xlo[(size_t)v * 64 + c * 4]) = ll;
  }
  sqf[v] = (float)s;
}

// ------- K1: fused gram sweep + per-lane top-14 queues -> per-quarter top-40 -
// grid (49, 4, 8): 64-row strip x col-quarter x sample. block 256 (4 waves);
// wave w rows w*16..w*16+15; lane (tx,qd) rows qd*4+e, cols f*16+tx.
// Quarter lane-class ~48-52 cols -> lambda 2.5, depth-14: P(miss) ~7e-8.
__global__ __launch_bounds__(256, 4) void k_sweep(
    const ushort* __restrict__ xhi, const ushort* __restrict__ xlo,
    const float* __restrict__ sqf, unsigned* __restrict__ candq) {
  const int ib = blockIdx.x, qt = blockIdx.y, b = blockIdx.z;
  const int r0 = ib * 64;
  const int jb0 = qt * 768;
  const int ntile = (qt == 3) ? 13 : 12;  // 3*768 + 832 = 3136
  const size_t bbase = (size_t)b * cL;

  __shared__ ushort aHi[64 * 72], aLo[64 * 72];  // stride 72: conflict-free
  __shared__ ushort bHi[64 * 72], bLo[64 * 72];
  __shared__ float sqJs[64];

  const int t  = threadIdx.x;
  const int ln = t & 63;
  const int w  = t >> 6;
  const int tx = ln & 15;
  const int qd = ln >> 4;

#pragma unroll
  for (int it = 0; it < 2; ++it) {  // stage A strip once (hi+lo)
    int idx = t + 256 * it;
    int r = idx >> 3, blk = idx & 7;
    *reinterpret_cast<uint4*>(&aHi[r * 72 + blk * 8]) =
        *reinterpret_cast<const uint4*>(&xhi[(bbase + r0 + r) * 64 + blk * 8]);
    *reinterpret_cast<uint4*>(&aLo[r * 72 + blk * 8]) =
        *reinterpret_cast<const uint4*>(&xlo[(bbase + r0 + r) * 64 + blk * 8]);
  }
  __syncthreads();

  bf16x8 aH[2], aL[2];
#pragma unroll
  for (int kk = 0; kk < 2; ++kk) {
    aH[kk] = *reinterpret_cast<const bf16x8*>(
        &aHi[(w * 16 + tx) * 72 + kk * 32 + qd * 8]);
    aL[kk] = *reinterpret_cast<const bf16x8*>(
        &aLo[(w * 16 + tx) * 72 + kk * 32 + qd * 8]);
  }

  unsigned q[4][14];  // per-row sorted top-14 (ascending), packed q16|col12
  float thr[4];       // float-domain gate = (q[e][13]>>12)+1 (exact semantics)
#pragma unroll
  for (int e = 0; e < 4; ++e) {
    thr[e] = 3.0e38f;
#pragma unroll
    for (int k = 0; k < 14; ++k) q[e][k] = 0xFFFFFFFFu;
  }

  for (int st = 0; st < ntile; ++st) {
    const int jb = jb0 + st * 64;
#pragma unroll
    for (int it = 0; it < 2; ++it) {  // stage B tile
      int idx = t + 256 * it;
      int r = idx >> 3, blk = idx & 7;
      *reinterpret_cast<uint4*>(&bHi[r * 72 + blk * 8]) =
          *reinterpret_cast<const uint4*>(&xhi[(bbase + jb + r) * 64 + blk * 8]);
      *reinterpret_cast<uint4*>(&bLo[r * 72 + blk * 8]) =
          *reinterpret_cast<const uint4*>(&xlo[(bbase + jb + r) * 64 + blk * 8]);
    }
    if (t < 64) sqJs[t] = sqf[bbase + jb + t];
    __syncthreads();

    float d2v[4][4];
#pragma unroll
    for (int f = 0; f < 4; ++f) {
      const int bro = (f * 16 + tx) * 72 + qd * 8;
      bf16x8 bh0 = *reinterpret_cast<const bf16x8*>(&bHi[bro]);
      bf16x8 bh1 = *reinterpret_cast<const bf16x8*>(&bHi[bro + 32]);
      bf16x8 bl0 = *reinterpret_cast<const bf16x8*>(&bLo[bro]);
      bf16x8 bl1 = *reinterpret_cast<const bf16x8*>(&bLo[bro + 32]);
      floatx4 acc = {0.f, 0.f, 0.f, 0.f};
      acc = __builtin_amdgcn_mfma_f32_16x16x32_bf16(aH[0], bh0, acc, 0, 0, 0);
      acc = __builtin_amdgcn_mfma_f32_16x16x32_bf16(aH[1], bh1, acc, 0, 0, 0);
      acc = __builtin_amdgcn_mfma_f32_16x16x32_bf16(aH[0], bl0, acc, 0, 0, 0);
      acc = __builtin_amdgcn_mfma_f32_16x16x32_bf16(aH[1], bl1, acc, 0, 0, 0);
      acc = __builtin_amdgcn_mfma_f32_16x16x32_bf16(aL[0], bh0, acc, 0, 0, 0);
      acc = __builtin_amdgcn_mfma_f32_16x16x32_bf16(aL[1], bh1, acc, 0, 0, 0);
      const float sj = sqJs[f * 16 + tx];
#pragma unroll
      for (int e = 0; e < 4; ++e) d2v[f][e] = sj - 2.0f * acc[e];
    }

    // selection: common path = 1 float cmp; pack+bubble only on pass
#pragma unroll
    for (int e = 0; e < 4; ++e) {
#pragma unroll
      for (int f = 0; f < 4; ++f) {
        float qf = fmaf(d2v[f][e], 64.f, 32768.f);
        if (qf < thr[e]) {
          float qc = fminf(fmaxf(qf, 0.f), 65535.f);
          unsigned p = ((unsigned)qc << 12) | (unsigned)(jb + f * 16 + tx);
          if (p < q[e][13]) {
            q[e][13] = p;
#pragma unroll
            for (int k = 13; k > 0; --k) {
              unsigned a = q[e][k - 1], c = q[e][k];
              q[e][k - 1] = umin2(a, c);
              q[e][k] = umax2(a, c);
            }
            thr[e] = (float)((q[e][13] >> 12) + 1);
          }
        }
      }
    }
    __syncthreads();  // protect B tiles before next staging
  }

  // extraction: per row, 40 wave-min steps over 16 tx-lane queue heads
#pragma unroll
  for (int e = 0; e < 4; ++e) {
    const size_t rowG = bbase + r0 + w * 16 + qd * 4 + e;
    unsigned* cr = candq + rowG * 160 + qt * 40;
    for (int it = 0; it < 40; ++it) {
      unsigned h = q[e][0];
      unsigned m = h;
      m = umin2(m, (unsigned)__shfl_xor((int)m, 1));
      m = umin2(m, (unsigned)__shfl_xor((int)m, 2));
      m = umin2(m, (unsigned)__shfl_xor((int)m, 4));
      m = umin2(m, (unsigned)__shfl_xor((int)m, 8));
      if (tx == 0) cr[it] = m;
      if (h == m) {  // unique (distinct cols) -> exactly one lane pops
#pragma unroll
        for (int k = 0; k < 13; ++k) q[e][k] = q[e][k + 1];
        q[e][13] = 0xFFFFFFFFu;
      }
    }
  }
}

// ------- K2: merge 4 sorted lists + conditional fp64 re-rank -> top-30 -----
__global__ __launch_bounds__(256) void k_rescore(const float* __restrict__ x,
                                                 const unsigned* __restrict__ candq,
                                                 int* __restrict__ nbr,
                                                 int* __restrict__ cnt) {
  const int w  = threadIdx.x >> 6;
  const int ln = threadIdx.x & 63;
  const size_t row = (size_t)blockIdx.x * 4 + w;
  const size_t bvert = row - (row % cL);  // b*cL

  const unsigned* cq = candq + row * 160;
  unsigned A = (ln < 40) ? cq[ln]       : 0xFFFFFFFFu;
  unsigned B = (ln < 40) ? cq[40 + ln]  : 0xFFFFFFFFu;
  unsigned C = (ln < 40) ? cq[80 + ln]  : 0xFFFFFFFFu;
  unsigned D = (ln < 40) ? cq[120 + ln] : 0xFFFFFFFFu;

  // split-min + bitonic clean: sorted lower-64 at each level
  unsigned s1 = umin2(A, (unsigned)__shfl((int)B, 63 - ln));
  s1 = bclean64(s1, ln);
  unsigned s2 = umin2(C, (unsigned)__shfl((int)D, 63 - ln));
  s2 = bclean64(s2, ln);
  unsigned g = umin2(s1, (unsigned)__shfl((int)s2, 63 - ln));
  g = bclean64(g, ln);  // sorted asc; lanes 0..39 = global top-40 (all real)

  const unsigned qv = g >> 12;
  const int col = (int)(g & 0xFFFu);

  // quantized gap at the 29/30 boundary (sorted -> just neighbors)
  unsigned q29 = (unsigned)__shfl((int)qv, 29);
  unsigned q30 = (unsigned)__shfl((int)qv, 30);
  // error budget: 1 unit quant truncation + ~0.1 unit bf16-split; 3 = 2x margin
  if (q30 > q29 + 3) {
    if (ln < cK) {
      nbr[row * cK + ln] = col;  // rank == lane (sorted)
      atomicAdd(&cnt[bvert + col], 1);
    }
    return;
  }

  // ambiguous boundary: exact fp64 re-rank of the 40 merged candidates
  float4 xi[16];
  const float4* xi4 = reinterpret_cast<const float4*>(x + row * 64);
#pragma unroll
  for (int c = 0; c < 16; ++c) xi[c] = xi4[c];

  double dv = 1e300;
  if (ln < 40) {
    const float4* xj4 = reinterpret_cast<const float4*>(x + (bvert + col) * 64);
    double ax = 0.0, ay = 0.0, az = 0.0, aw = 0.0;
#pragma unroll
    for (int c = 0; c < 16; ++c) {
      float4 xj = xj4[c];
      double d0 = (double)xi[c].x - (double)xj.x; ax = fma(d0, d0, ax);
      double d1 = (double)xi[c].y - (double)xj.y; ay = fma(d1, d1, ay);
      double d2 = (double)xi[c].z - (double)xj.z; az = fma(d2, d2, az);
      double d3 = (double)xi[c].w - (double)xj.w; aw = fma(d3, d3, aw);
    }
    dv = (ax + ay) + (az + aw);
  }
  int r2 = 0;
  for (int j = 0; j < 40; ++j) {
    double od = __shfl(dv, j);
    r2 += (od < dv || (od == dv && j < ln)) ? 1 : 0;
  }
  if (ln < 40 && r2 < cK) {
    nbr[row * cK + r2] = col;
    atomicAdd(&cnt[bvert + col], 1);
  }
}

// ------- CSR: scan + fill (vertex -> edges containing it) -------
__global__ void k_scan(const int* __restrict__ cnt, int* __restrict__ rp) {
  int b = blockIdx.x;
  int ln = threadIdx.x;  // block = 64 = one wave
  const int* c = cnt + b * cL;
  int* r = rp + b * (cL + 1);
  int carry = 0;
  for (int base = 0; base < cL; base += 64) {  // 3136 = 49*64
    int v = c[base + ln];
    int s = v;
#pragma unroll
    for (int off = 1; off < 64; off <<= 1) {
      int u = __shfl_up(s, off);
      if (ln >= off) s += u;
    }
    r[base + ln] = carry + s - v;  // exclusive
    carry += __shfl(s, 63);
  }
  if (ln == 63) r[cL] = carry;
}

__global__ void k_fill(const int* __restrict__ nbr, const int* __restrict__ rp,
                       int* __restrict__ cur, int* __restrict__ el) {
  int g = blockIdx.x * 256 + threadIdx.x;
  if (g >= NV * cK) return;
  int b = g / (cL * cK);
  int e = (g / cK) % cL;
  int v = nbr[g];
  int p = rp[b * (cL + 1) + v] + atomicAdd(&cur[b * cL + v], 1);
  el[(size_t)b * cL * cK + p] = e;
}

// ------- theta1 + bn (eval), bf16 out -------
__global__ __launch_bounds__(256) void k_theta1(const float* __restrict__ x,
                                                const float* __restrict__ w1,
                                                const float* __restrict__ b1,
                                                const float* __restrict__ g1,
                                                const float* __restrict__ be1,
                                                __bf16* __restrict__ h1) {
  __shared__ float w[cC * cH];
  int t = threadIdx.x;
  for (int n = t; n < cC * cH; n += 256) w[n] = w1[n];
  __syncthreads();
  int g = blockIdx.x * 256 + t;
  int row = g >> 5;
  int f = g & 31;
  const float4* xr = reinterpret_cast<const float4*>(x) + (size_t)row * 16;
  float s = 0.f;
#pragma unroll
  for (int kc = 0; kc < 16; ++kc) {
    float4 xv = xr[kc];
    s += xv.x * w[(4 * kc + 0) * cH + f];
    s += xv.y * w[(4 * kc + 1) * cH + f];
    s += xv.z * w[(4 * kc + 2) * cH + f];
    s += xv.w * w[(4 * kc + 3) * cH + f];
  }
  h1[g] = (__bf16)((s + b1[f]) * (g1[f] * BN_SC) + be1[f]);
}

// ------- v2e F=32 (wave/edge; all 15 gathers per half independent) -------
__global__ __launch_bounds__(256) void k_v2e32(const __bf16* __restrict__ X,
                                               const int* __restrict__ nbr,
                                               __bf16* __restrict__ Y) {
  const int w  = threadIdx.x >> 6;
  const int ln = threadIdx.x & 63;
  const size_t er = (size_t)blockIdx.x * 4 + w;  // b*cL + e
  const size_t b  = er / cL;
  const __bf16* Xb = X + b * cL * cH;
  const int nb_l = nbr[er * cK + (ln < cK ? ln : cK - 1)];
  const int hi = ln >> 5, f = ln & 31;
  int idx[15];
#pragma unroll
  for (int m = 0; m < 15; ++m) idx[m] = __shfl(nb_l, hi + 2 * m);
  float y[15];
#pragma unroll
  for (int m = 0; m < 15; ++m) y[m] = (float)Xb[(size_t)idx[m] * cH + f];
  float s = 0.f;
#pragma unroll
  for (int m = 0; m < 15; ++m) s += y[m];
  s += __shfl_xor(s, 32);
  if (hi == 0) Y[er * cH + f] = (__bf16)(s * (1.f / 30.f));
}

// ------- e2v(F=32) + relu + theta2 + bn fused (wave per vertex) -------
__global__ __launch_bounds__(256) void k_e2v_t2(const __bf16* __restrict__ Y,
                                                const int* __restrict__ rp,
                                                const int* __restrict__ el,
                                                const float* __restrict__ w2,
                                                const float* __restrict__ b2,
                                                const float* __restrict__ g2,
                                                const float* __restrict__ be2,
                                                __bf16* __restrict__ h2) {
  __shared__ float w2s[cH * cC];  // 8 KB
  {
    int t = threadIdx.x;
    for (int n = t; n < cH * cC; n += 256) w2s[n] = w2[n];
  }
  const int w  = threadIdx.x >> 6;
  const int ln = threadIdx.x & 63;
  const size_t vr = (size_t)blockIdx.x * 4 + w;  // b*cL + v
  const size_t b  = vr / cL;
  const int v = (int)(vr % cL);
  const int* rpb = rp + b * (cL + 1);
  const int s0 = rpb[v];
  const int deg = rpb[v + 1] - s0;  // >= 1 (self edge always selected)
  const int* elb = el + b * (size_t)cL * cK + s0;
  const __bf16* Yb = Y + b * cL * cH;
  const int hi = ln >> 5, f = ln & 31;
  float s = 0.f;

  for (int base = 0; base < deg; base += 64) {
    const int take = min(64, deg - base);
    const int eidx = elb[base + (ln < take ? ln : 0)];  // parallel load
    for (int j0 = 0; j0 < take; j0 += 16) {  // 8 independent per half
      float acc = 0.f;
#pragma unroll
      for (int k2 = 0; k2 < 8; ++k2) {
        int j = j0 + 2 * k2 + hi;
        int e0 = __shfl(eidx, j < take ? j : 0);
        float y = (float)Yb[(size_t)e0 * cH + f];
        acc += (j < take) ? y : 0.f;
      }
      s += acc;
    }
  }
  __syncthreads();  // w2s ready

  s += __shfl_xor(s, 32);
  float r = fmaxf(s / (float)deg, 0.f);  // e2v mean + relu

  float s2 = 0.f;
#pragma unroll 8
  for (int k = 0; k < cH; ++k) {
    float rk = __shfl(r, k);
    s2 = fmaf(rk, w2s[k * cC + ln], s2);
  }
  h2[vr * cC + ln] = (__bf16)((s2 + b2[ln]) * (g2[ln] * BN_SC) + be2[ln]);
}

// ------- v2e F=64 (wave/edge; all 30 gathers independent) -------
__global__ __launch_bounds__(256) void k_v2e64(const __bf16* __restrict__ X,
                                               const int* __restrict__ nbr,
                                               __bf16* __restrict__ Y) {
  const int w  = threadIdx.x >> 6;
  const int ln = threadIdx.x & 63;
  const size_t er = (size_t)blockIdx.x * 4 + w;  // b*cL + e
  const size_t b  = er / cL;
  const __bf16* Xb = X + b * cL * cC;
  const int nb_l = nbr[er * cK + (ln < cK ? ln : cK - 1)];
  int idx[30];
#pragma unroll
  for (int m = 0; m < 30; ++m) idx[m] = __shfl(nb_l, m);
  float y[30];
#pragma unroll
  for (int m = 0; m < 30; ++m) y[m] = (float)Xb[(size_t)idx[m] * cC + ln];
  float s = 0.f;
#pragma unroll
  for (int m = 0; m < 30; ++m) s += y[m];
  Y[er * cC + ln] = (__bf16)(s * (1.f / 30.f));
}

// ------- final e2v (F=64, no relu), fp32 out -------
__global__ __launch_bounds__(256) void k_e2v64(const __bf16* __restrict__ Y,
                                               const int* __restrict__ rp,
                                               const int* __restrict__ el,
                                               float* __restrict__ out) {
  const int w  = threadIdx.x >> 6;
  const int ln = threadIdx.x & 63;
  const size_t vr = (size_t)blockIdx.x * 4 + w;  // b*cL + v
  const size_t b  = vr / cL;
  const int v = (int)(vr % cL);
  const int* rpb = rp + b * (cL + 1);
  const int s0 = rpb[v];
  const int deg = rpb[v + 1] - s0;
  const int* elb = el + b * (size_t)cL * cK + s0;
  const __bf16* Yb = Y + b * cL * cC;
  float s = 0.f;

  for (int base = 0; base < deg; base += 64) {
    const int take = min(64, deg - base);
    const int eidx = elb[base + (ln < take ? ln : 0)];
    for (int j0 = 0; j0 < take; j0 += 8) {  // 8 independent gathers
      float acc = 0.f;
#pragma unroll
      for (int k2 = 0; k2 < 8; ++k2) {
        int j = j0 + k2;
        int e0 = __shfl(eidx, j < take ? j : 0);
        float y = (float)Yb[(size_t)e0 * cC + ln];
        acc += (j < take) ? y : 0.f;
      }
      s += acc;
    }
  }
  out[vr * cC + ln] = s / (float)deg;
}

}  // namespace

extern "C" void kernel_launch(void* const* d_in, const int* in_sizes, int n_in,
                              void* d_out, int out_size, void* d_ws,
                              size_t ws_size, hipStream_t stream) {
  (void)in_sizes; (void)n_in; (void)out_size; (void)ws_size;
  const float* x   = (const float*)d_in[0];
  const float* w1  = (const float*)d_in[1];
  const float* b1  = (const float*)d_in[2];
  const float* g1  = (const float*)d_in[3];
  const float* be1 = (const float*)d_in[4];
  const float* w2  = (const float*)d_in[5];
  const float* b2  = (const float*)d_in[6];
  const float* g2  = (const float*)d_in[7];
  const float* be2 = (const float*)d_in[8];
  float* out = (float*)d_out;

  // workspace: ~26 MB peak (<= R5's proven ~31.5 MB)
  char* base = (char*)d_ws;
  size_t off = 0;
  auto carve = [&](size_t bytes) {
    char* p = base + off;
    off += (bytes + 255) & ~(size_t)255;
    return p;
  };
  float* sqf = (float*)carve((size_t)NV * 4);
  int*   nbr = (int*)carve((size_t)NV * cK * 4);
  int*   rp  = (int*)carve((size_t)cB * (cL + 1) * 4);
  int*   cnt = (int*)carve((size_t)NV * 4);
  int*   cur = (int*)carve((size_t)NV * 4);
  // region A: {xhi|xlo} (dead after k_sweep) then {el}
  char* RA = carve((size_t)NV * 64 * 2 * 2);  // 6,422,528
  ushort* xhi = (ushort*)RA;
  ushort* xlo = (ushort*)(RA + 3211264);
  int* el = (int*)RA;
  // region C: candq (16 MB, dead after rescore) then bf16 activations
  char* RC = carve((size_t)NV * 160 * 4);  // 16,056,320
  unsigned* candq = (unsigned*)RC;
  __bf16* h1 = (__bf16*)RC;                 // 1.6 MB
  __bf16* Y1 = (__bf16*)(RC + 1605632);     // 1.6 MB
  __bf16* h2 = (__bf16*)(RC + 3211264);     // 3.2 MB
  __bf16* Y2 = (__bf16*)(RC + 6422528);     // 3.2 MB

  k_split<<<(NV + 255) / 256, 256, 0, stream>>>(x, xhi, xlo, sqf, cnt, cur);
  k_sweep<<<dim3(49, 4, cB), 256, 0, stream>>>(xhi, xlo, sqf, candq);
  k_rescore<<<NV / 4, 256, 0, stream>>>(x, candq, nbr, cnt);

  k_scan<<<cB, 64, 0, stream>>>(cnt, rp);
  k_fill<<<(NV * cK) / 256, 256, 0, stream>>>(nbr, rp, cur, el);

  k_theta1<<<NV * cH / 256, 256, 0, stream>>>(x, w1, b1, g1, be1, h1);
  k_v2e32<<<NV / 4, 256, 0, stream>>>(h1, nbr, Y1);
  k_e2v_t2<<<NV / 4, 256, 0, stream>>>(Y1, rp, el, w2, b2, g2, be2, h2);
  k_v2e64<<<NV / 4, 256, 0, stream>>>(h2, nbr, Y2);
  k_e2v64<<<NV / 4, 256, 0, stream>>>(Y2, rp, el, out);
}

// Round 8
// 487.421 us; speedup vs baseline: 11.1790x; 1.0411x over previous
//
#include <hip/hip_runtime.h>
#include <math.h>

// HGNNPBlock: per-sample kNN hypergraph (k=30) + 2x (theta -> bn -> v2v mean).
// B=8, L=56*56=3136, C=64, hid=32.
//
// R8 sweep rebalance: 128-thread blocks (2 waves) x 32-row strips x column
// quarters -> grid 3136 (12.25/CU), 18.6 KB LDS -> 8 blocks/CU -> ~50% occ
// (R7: 33% occ but quartering had raised selection work 1.5x -- net wash).
// Queue depth 14->10 (lambda=0.63/class -> overflow P~1.6e-10): bubbles
// 26->18 ops. Class structure (c~49 cols/lane-row), MFMA math, extraction,
// merge-rescore, CSR + bf16 gather tail all unchanged from R7.

namespace {

constexpr int cB = 8;
constexpr int cL = 3136;
constexpr int cC = 64;
constexpr int cH = 32;
constexpr int cK = 30;
constexpr int NV = cB * cL;   // 25088
constexpr int QD = 10;        // per-lane queue depth
constexpr float BN_SC = 0.99999500003749964f;  // 1/sqrt(1+1e-5) in fp32

typedef __bf16 bf16x4 __attribute__((ext_vector_type(4)));
typedef __bf16 bf16x8 __attribute__((ext_vector_type(8)));
typedef float floatx4 __attribute__((ext_vector_type(4)));

__device__ inline unsigned umin2(unsigned a, unsigned b) { return a < b ? a : b; }
__device__ inline unsigned umax2(unsigned a, unsigned b) { return a > b ? a : b; }

// sort a bitonic 64-sequence (one value per lane) ascending, shfl-only
__device__ inline unsigned bclean64(unsigned v, int ln) {
#pragma unroll
  for (int off = 32; off; off >>= 1) {
    unsigned p = (unsigned)__shfl_xor((int)v, off);
    v = (ln & off) ? umax2(v, p) : umin2(v, p);
  }
  return v;
}

// ------- K0: split x into bf16 hi/lo + fp32 |x|^2; zero cnt/cur -------
__global__ void k_split(const float* __restrict__ x, ushort* __restrict__ xhi,
                        ushort* __restrict__ xlo, float* __restrict__ sqf,
                        int* __restrict__ cnt, int* __restrict__ cur) {
  int v = blockIdx.x * 256 + threadIdx.x;
  if (v >= NV) return;
  cnt[v] = 0;
  cur[v] = 0;
  const float4* p = reinterpret_cast<const float4*>(x) + (size_t)v * 16;
  double s = 0.0;
#pragma unroll
  for (int c = 0; c < 16; ++c) {
    float4 f = p[c];
    bf16x4 hh, ll;
#pragma unroll
    for (int e = 0; e < 4; ++e) {
      float a = (&f.x)[e];
      __bf16 h = (__bf16)a;
      ll[e] = (__bf16)(a - (float)h);
      hh[e] = h;
      s += (double)a * (double)a;
    }
    *reinterpret_cast<bf16x4*>(&xhi[(size_t)v * 64 + c * 4]) = hh;
    *reinterpret_cast<bf16x4*>(&xlo[(size_t)v * 64 + c * 4]) = ll;
  }
  sqf[v] = (float)s;
}

// ------- K1: fused gram sweep + per-lane top-10 queues -> per-quarter top-40 -
// grid (98, 4, 8): 32-row strip x col-quarter x sample. block 128 (2 waves);
// wave w rows w*16..w*16+15; lane (tx,qd) rows qd*4+e, cols f*16+tx (f<2).
// B tiles 32 cols x 64 feats. Lane-class ~49-52 cols -> lambda 0.63-0.66;
// depth-10 overflow P ~1.6e-10 -> ~1e-3 expected misses per run.
__global__ __launch_bounds__(128, 4) void k_sweep(
    const ushort* __restrict__ xhi, const ushort* __restrict__ xlo,
    const float* __restrict__ sqf, unsigned* __restrict__ candq) {
  const int ib = blockIdx.x, qt = blockIdx.y, b = blockIdx.z;
  const int r0 = ib * 32;
  const int jb0 = qt * 768;
  const int ntile = (qt == 3) ? 26 : 24;  // 32-col tiles; 3*768 + 832 = 3136
  const size_t bbase = (size_t)b * cL;

  __shared__ ushort aHi[32 * 72], aLo[32 * 72];  // stride 72: conflict-free
  __shared__ ushort bHi[32 * 72], bLo[32 * 72];
  __shared__ float sqJs[32];

  const int t  = threadIdx.x;  // 0..127
  const int ln = t & 63;
  const int w  = t >> 6;       // wave -> 16-row group
  const int tx = ln & 15;
  const int qd = ln >> 4;

#pragma unroll
  for (int it = 0; it < 2; ++it) {  // stage A strip (32 rows x 8 uint4 chunks)
    int idx = t + 128 * it;
    int r = idx >> 3, blk = idx & 7;
    *reinterpret_cast<uint4*>(&aHi[r * 72 + blk * 8]) =
        *reinterpret_cast<const uint4*>(&xhi[(bbase + r0 + r) * 64 + blk * 8]);
    *reinterpret_cast<uint4*>(&aLo[r * 72 + blk * 8]) =
        *reinterpret_cast<const uint4*>(&xlo[(bbase + r0 + r) * 64 + blk * 8]);
  }
  __syncthreads();

  bf16x8 aH[2], aL[2];
#pragma unroll
  for (int kk = 0; kk < 2; ++kk) {
    aH[kk] = *reinterpret_cast<const bf16x8*>(
        &aHi[(w * 16 + tx) * 72 + kk * 32 + qd * 8]);
    aL[kk] = *reinterpret_cast<const bf16x8*>(
        &aLo[(w * 16 + tx) * 72 + kk * 32 + qd * 8]);
  }

  unsigned q[4][QD];  // per-row sorted top-QD (ascending), packed q16|col12
  float thr[4];       // float-domain gate = (q[e][QD-1]>>12)+1
#pragma unroll
  for (int e = 0; e < 4; ++e) {
    thr[e] = 3.0e38f;
#pragma unroll
    for (int k = 0; k < QD; ++k) q[e][k] = 0xFFFFFFFFu;
  }

  for (int st = 0; st < ntile; ++st) {
    const int jb = jb0 + st * 32;
#pragma unroll
    for (int it = 0; it < 2; ++it) {  // stage B tile (32 cols x 8 chunks)
      int idx = t + 128 * it;
      int r = idx >> 3, blk = idx & 7;
      *reinterpret_cast<uint4*>(&bHi[r * 72 + blk * 8]) =
          *reinterpret_cast<const uint4*>(&xhi[(bbase + jb + r) * 64 + blk * 8]);
      *reinterpret_cast<uint4*>(&bLo[r * 72 + blk * 8]) =
          *reinterpret_cast<const uint4*>(&xlo[(bbase + jb + r) * 64 + blk * 8]);
    }
    if (t < 32) sqJs[t] = sqf[bbase + jb + t];
    __syncthreads();

    float d2v[2][4];
#pragma unroll
    for (int f = 0; f < 2; ++f) {
      const int bro = (f * 16 + tx) * 72 + qd * 8;
      bf16x8 bh0 = *reinterpret_cast<const bf16x8*>(&bHi[bro]);
      bf16x8 bh1 = *reinterpret_cast<const bf16x8*>(&bHi[bro + 32]);
      bf16x8 bl0 = *reinterpret_cast<const bf16x8*>(&bLo[bro]);
      bf16x8 bl1 = *reinterpret_cast<const bf16x8*>(&bLo[bro + 32]);
      floatx4 acc = {0.f, 0.f, 0.f, 0.f};
      acc = __builtin_amdgcn_mfma_f32_16x16x32_bf16(aH[0], bh0, acc, 0, 0, 0);
      acc = __builtin_amdgcn_mfma_f32_16x16x32_bf16(aH[1], bh1, acc, 0, 0, 0);
      acc = __builtin_amdgcn_mfma_f32_16x16x32_bf16(aH[0], bl0, acc, 0, 0, 0);
      acc = __builtin_amdgcn_mfma_f32_16x16x32_bf16(aH[1], bl1, acc, 0, 0, 0);
      acc = __builtin_amdgcn_mfma_f32_16x16x32_bf16(aL[0], bh0, acc, 0, 0, 0);
      acc = __builtin_amdgcn_mfma_f32_16x16x32_bf16(aL[1], bh1, acc, 0, 0, 0);
      const float sj = sqJs[f * 16 + tx];
#pragma unroll
      for (int e = 0; e < 4; ++e) d2v[f][e] = sj - 2.0f * acc[e];
    }

    // selection: common path = 1 fmaf + 1 float cmp; pack+bubble on pass only
#pragma unroll
    for (int e = 0; e < 4; ++e) {
#pragma unroll
      for (int f = 0; f < 2; ++f) {
        float qf = fmaf(d2v[f][e], 64.f, 32768.f);
        if (qf < thr[e]) {
          float qc = fminf(fmaxf(qf, 0.f), 65535.f);
          unsigned p = ((unsigned)qc << 12) | (unsigned)(jb + f * 16 + tx);
          if (p < q[e][QD - 1]) {
            q[e][QD - 1] = p;
#pragma unroll
            for (int k = QD - 1; k > 0; --k) {
              unsigned a = q[e][k - 1], c = q[e][k];
              q[e][k - 1] = umin2(a, c);
              q[e][k] = umax2(a, c);
            }
            thr[e] = (float)((q[e][QD - 1] >> 12) + 1);
          }
        }
      }
    }
    __syncthreads();  // protect B tiles before next staging
  }

  // extraction: per row, 40 wave-min steps over 16 tx-lane queue heads
  // (capacity 16*QD=160 >= 40; every class has >= QD real values)
#pragma unroll
  for (int e = 0; e < 4; ++e) {
    const size_t rowG = bbase + r0 + w * 16 + qd * 4 + e;
    unsigned* cr = candq + rowG * 160 + qt * 40;
    for (int it = 0; it < 40; ++it) {
      unsigned h = q[e][0];
      unsigned m = h;
      m = umin2(m, (unsigned)__shfl_xor((int)m, 1));
      m = umin2(m, (unsigned)__shfl_xor((int)m, 2));
      m = umin2(m, (unsigned)__shfl_xor((int)m, 4));
      m = umin2(m, (unsigned)__shfl_xor((int)m, 8));
      if (tx == 0) cr[it] = m;
      if (h == m) {  // unique (distinct cols) -> exactly one lane pops
#pragma unroll
        for (int k = 0; k < QD - 1; ++k) q[e][k] = q[e][k + 1];
        q[e][QD - 1] = 0xFFFFFFFFu;
      }
    }
  }
}

// ------- K2: merge 4 sorted lists + conditional fp64 re-rank -> top-30 -----
__global__ __launch_bounds__(256) void k_rescore(const float* __restrict__ x,
                                                 const unsigned* __restrict__ candq,
                                                 int* __restrict__ nbr,
                                                 int* __restrict__ cnt) {
  const int w  = threadIdx.x >> 6;
  const int ln = threadIdx.x & 63;
  const size_t row = (size_t)blockIdx.x * 4 + w;
  const size_t bvert = row - (row % cL);  // b*cL

  const unsigned* cq = candq + row * 160;
  unsigned A = (ln < 40) ? cq[ln]       : 0xFFFFFFFFu;
  unsigned B = (ln < 40) ? cq[40 + ln]  : 0xFFFFFFFFu;
  unsigned C = (ln < 40) ? cq[80 + ln]  : 0xFFFFFFFFu;
  unsigned D = (ln < 40) ? cq[120 + ln] : 0xFFFFFFFFu;

  // split-min + bitonic clean: sorted lower-64 at each level
  unsigned s1 = umin2(A, (unsigned)__shfl((int)B, 63 - ln));
  s1 = bclean64(s1, ln);
  unsigned s2 = umin2(C, (unsigned)__shfl((int)D, 63 - ln));
  s2 = bclean64(s2, ln);
  unsigned g = umin2(s1, (unsigned)__shfl((int)s2, 63 - ln));
  g = bclean64(g, ln);  // sorted asc; lanes 0..39 = global top-40 (all real)

  const unsigned qv = g >> 12;
  const int col = (int)(g & 0xFFFu);

  // quantized gap at the 29/30 boundary (sorted -> just neighbors)
  unsigned q29 = (unsigned)__shfl((int)qv, 29);
  unsigned q30 = (unsigned)__shfl((int)qv, 30);
  // error budget: 1 unit quant truncation + ~0.1 unit bf16-split; 3 = 2x margin
  if (q30 > q29 + 3) {
    if (ln < cK) {
      nbr[row * cK + ln] = col;  // rank == lane (sorted)
      atomicAdd(&cnt[bvert + col], 1);
    }
    return;
  }

  // ambiguous boundary: exact fp64 re-rank of the 40 merged candidates
  float4 xi[16];
  const float4* xi4 = reinterpret_cast<const float4*>(x + row * 64);
#pragma unroll
  for (int c = 0; c < 16; ++c) xi[c] = xi4[c];

  double dv = 1e300;
  if (ln < 40) {
    const float4* xj4 = reinterpret_cast<const float4*>(x + (bvert + col) * 64);
    double ax = 0.0, ay = 0.0, az = 0.0, aw = 0.0;
#pragma unroll
    for (int c = 0; c < 16; ++c) {
      float4 xj = xj4[c];
      double d0 = (double)xi[c].x - (double)xj.x; ax = fma(d0, d0, ax);
      double d1 = (double)xi[c].y - (double)xj.y; ay = fma(d1, d1, ay);
      double d2 = (double)xi[c].z - (double)xj.z; az = fma(d2, d2, az);
      double d3 = (double)xi[c].w - (double)xj.w; aw = fma(d3, d3, aw);
    }
    dv = (ax + ay) + (az + aw);
  }
  int r2 = 0;
  for (int j = 0; j < 40; ++j) {
    double od = __shfl(dv, j);
    r2 += (od < dv || (od == dv && j < ln)) ? 1 : 0;
  }
  if (ln < 40 && r2 < cK) {
    nbr[row * cK + r2] = col;
    atomicAdd(&cnt[bvert + col], 1);
  }
}

// ------- CSR: scan + fill (vertex -> edges containing it) -------
__global__ void k_scan(const int* __restrict__ cnt, int* __restrict__ rp) {
  int b = blockIdx.x;
  int ln = threadIdx.x;  // block = 64 = one wave
  const int* c = cnt + b * cL;
  int* r = rp + b * (cL + 1);
  int carry = 0;
  for (int base = 0; base < cL; base += 64) {  // 3136 = 49*64
    int v = c[base + ln];
    int s = v;
#pragma unroll
    for (int off = 1; off < 64; off <<= 1) {
      int u = __shfl_up(s, off);
      if (ln >= off) s += u;
    }
    r[base + ln] = carry + s - v;  // exclusive
    carry += __shfl(s, 63);
  }
  if (ln == 63) r[cL] = carry;
}

__global__ void k_fill(const int* __restrict__ nbr, const int* __restrict__ rp,
                       int* __restrict__ cur, int* __restrict__ el) {
  int g = blockIdx.x * 256 + threadIdx.x;
  if (g >= NV * cK) return;
  int b = g / (cL * cK);
  int e = (g / cK) % cL;
  int v = nbr[g];
  int p = rp[b * (cL + 1) + v] + atomicAdd(&cur[b * cL + v], 1);
  el[(size_t)b * cL * cK + p] = e;
}

// ------- theta1 + bn (eval), bf16 out -------
__global__ __launch_bounds__(256) void k_theta1(const float* __restrict__ x,
                                                const float* __restrict__ w1,
                                                const float* __restrict__ b1,
                                                const float* __restrict__ g1,
                                                const float* __restrict__ be1,
                                                __bf16* __restrict__ h1) {
  __shared__ float w[cC * cH];
  int t = threadIdx.x;
  for (int n = t; n < cC * cH; n += 256) w[n] = w1[n];
  __syncthreads();
  int g = blockIdx.x * 256 + t;
  int row = g >> 5;
  int f = g & 31;
  const float4* xr = reinterpret_cast<const float4*>(x) + (size_t)row * 16;
  float s = 0.f;
#pragma unroll
  for (int kc = 0; kc < 16; ++kc) {
    float4 xv = xr[kc];
    s += xv.x * w[(4 * kc + 0) * cH + f];
    s += xv.y * w[(4 * kc + 1) * cH + f];
    s += xv.z * w[(4 * kc + 2) * cH + f];
    s += xv.w * w[(4 * kc + 3) * cH + f];
  }
  h1[g] = (__bf16)((s + b1[f]) * (g1[f] * BN_SC) + be1[f]);
}

// ------- v2e F=32 (wave/edge; all 15 gathers per half independent) -------
__global__ __launch_bounds__(256) void k_v2e32(const __bf16* __restrict__ X,
                                               const int* __restrict__ nbr,
                                               __bf16* __restrict__ Y) {
  const int w  = threadIdx.x >> 6;
  const int ln = threadIdx.x & 63;
  const size_t er = (size_t)blockIdx.x * 4 + w;  // b*cL + e
  const size_t b  = er / cL;
  const __bf16* Xb = X + b * cL * cH;
  const int nb_l = nbr[er * cK + (ln < cK ? ln : cK - 1)];
  const int hi = ln >> 5, f = ln & 31;
  int idx[15];
#pragma unroll
  for (int m = 0; m < 15; ++m) idx[m] = __shfl(nb_l, hi + 2 * m);
  float y[15];
#pragma unroll
  for (int m = 0; m < 15; ++m) y[m] = (float)Xb[(size_t)idx[m] * cH + f];
  float s = 0.f;
#pragma unroll
  for (int m = 0; m < 15; ++m) s += y[m];
  s += __shfl_xor(s, 32);
  if (hi == 0) Y[er * cH + f] = (__bf16)(s * (1.f / 30.f));
}

// ------- e2v(F=32) + relu + theta2 + bn fused (wave per vertex) -------
__global__ __launch_bounds__(256) void k_e2v_t2(const __bf16* __restrict__ Y,
                                                const int* __restrict__ rp,
                                                const int* __restrict__ el,
                                                const float* __restrict__ w2,
                                                const float* __restrict__ b2,
                                                const float* __restrict__ g2,
                                                const float* __restrict__ be2,
                                                __bf16* __restrict__ h2) {
  __shared__ float w2s[cH * cC];  // 8 KB
  {
    int t = threadIdx.x;
    for (int n = t; n < cH * cC; n += 256) w2s[n] = w2[n];
  }
  const int w  = threadIdx.x >> 6;
  const int ln = threadIdx.x & 63;
  const size_t vr = (size_t)blockIdx.x * 4 + w;  // b*cL + v
  const size_t b  = vr / cL;
  const int v = (int)(vr % cL);
  const int* rpb = rp + b * (cL + 1);
  const int s0 = rpb[v];
  const int deg = rpb[v + 1] - s0;  // >= 1 (self edge always selected)
  const int* elb = el + b * (size_t)cL * cK + s0;
  const __bf16* Yb = Y + b * cL * cH;
  const int hi = ln >> 5, f = ln & 31;
  float s = 0.f;

  for (int base = 0; base < deg; base += 64) {
    const int take = min(64, deg - base);
    const int eidx = elb[base + (ln < take ? ln : 0)];  // parallel load
    for (int j0 = 0; j0 < take; j0 += 16) {  // 8 independent per half
      float acc = 0.f;
#pragma unroll
      for (int k2 = 0; k2 < 8; ++k2) {
        int j = j0 + 2 * k2 + hi;
        int e0 = __shfl(eidx, j < take ? j : 0);
        float y = (float)Yb[(size_t)e0 * cH + f];
        acc += (j < take) ? y : 0.f;
      }
      s += acc;
    }
  }
  __syncthreads();  // w2s ready

  s += __shfl_xor(s, 32);
  float r = fmaxf(s / (float)deg, 0.f);  // e2v mean + relu

  float s2 = 0.f;
#pragma unroll 8
  for (int k = 0; k < cH; ++k) {
    float rk = __shfl(r, k);
    s2 = fmaf(rk, w2s[k * cC + ln], s2);
  }
  h2[vr * cC + ln] = (__bf16)((s2 + b2[ln]) * (g2[ln] * BN_SC) + be2[ln]);
}

// ------- v2e F=64 (wave/edge; all 30 gathers independent) -------
__global__ __launch_bounds__(256) void k_v2e64(const __bf16* __restrict__ X,
                                               const int* __restrict__ nbr,
                                               __bf16* __restrict__ Y) {
  const int w  = threadIdx.x >> 6;
  const int ln = threadIdx.x & 63;
  const size_t er = (size_t)blockIdx.x * 4 + w;  // b*cL + e
  const size_t b  = er / cL;
  const __bf16* Xb = X + b * cL * cC;
  const int nb_l = nbr[er * cK + (ln < cK ? ln : cK - 1)];
  int idx[30];
#pragma unroll
  for (int m = 0; m < 30; ++m) idx[m] = __shfl(nb_l, m);
  float y[30];
#pragma unroll
  for (int m = 0; m < 30; ++m) y[m] = (float)Xb[(size_t)idx[m] * cC + ln];
  float s = 0.f;
#pragma unroll
  for (int m = 0; m < 30; ++m) s += y[m];
  Y[er * cC + ln] = (__bf16)(s * (1.f / 30.f));
}

// ------- final e2v (F=64, no relu), fp32 out -------
__global__ __launch_bounds__(256) void k_e2v64(const __bf16* __restrict__ Y,
                                               const int* __restrict__ rp,
                                               const int* __restrict__ el,
                                               float* __restrict__ out) {
  const int w  = threadIdx.x >> 6;
  const int ln = threadIdx.x & 63;
  const size_t vr = (size_t)blockIdx.x * 4 + w;  // b*cL + v
  const size_t b  = vr / cL;
  const int v = (int)(vr % cL);
  const int* rpb = rp + b * (cL + 1);
  const int s0 = rpb[v];
  const int deg = rpb[v + 1] - s0;
  const int* elb = el + b * (size_t)cL * cK + s0;
  const __bf16* Yb = Y + b * cL * cC;
  float s = 0.f;

  for (int base = 0; base < deg; base += 64) {
    const int take = min(64, deg - base);
    const int eidx = elb[base + (ln < take ? ln : 0)];
    for (int j0 = 0; j0 < take; j0 += 8) {  // 8 independent gathers
      float acc = 0.f;
#pragma unroll
      for (int k2 = 0; k2 < 8; ++k2) {
        int j = j0 + k2;
        int e0 = __shfl(eidx, j < take ? j : 0);
        float y = (float)Yb[(size_t)e0 * cC + ln];
        acc += (j < take) ? y : 0.f;
      }
      s += acc;
    }
  }
  out[vr * cC + ln] = s / (float)deg;
}

}  // namespace

extern "C" void kernel_launch(void* const* d_in, const int* in_sizes, int n_in,
                              void* d_out, int out_size, void* d_ws,
                              size_t ws_size, hipStream_t stream) {
  (void)in_sizes; (void)n_in; (void)out_size; (void)ws_size;
  const float* x   = (const float*)d_in[0];
  const float* w1  = (const float*)d_in[1];
  const float* b1  = (const float*)d_in[2];
  const float* g1  = (const float*)d_in[3];
  const float* be1 = (const float*)d_in[4];
  const float* w2  = (const float*)d_in[5];
  const float* b2  = (const float*)d_in[6];
  const float* g2  = (const float*)d_in[7];
  const float* be2 = (const float*)d_in[8];
  float* out = (float*)d_out;

  // workspace: ~26 MB peak (<= proven ~31.5 MB)
  char* base = (char*)d_ws;
  size_t off = 0;
  auto carve = [&](size_t bytes) {
    char* p = base + off;
    off += (bytes + 255) & ~(size_t)255;
    return p;
  };
  float* sqf = (float*)carve((size_t)NV * 4);
  int*   nbr = (int*)carve((size_t)NV * cK * 4);
  int*   rp  = (int*)carve((size_t)cB * (cL + 1) * 4);
  int*   cnt = (int*)carve((size_t)NV * 4);
  int*   cur = (int*)carve((size_t)NV * 4);
  // region A: {xhi|xlo} (dead after k_sweep) then {el}
  char* RA = carve((size_t)NV * 64 * 2 * 2);  // 6,422,528
  ushort* xhi = (ushort*)RA;
  ushort* xlo = (ushort*)(RA + 3211264);
  int* el = (int*)RA;
  // region C: candq (16 MB, dead after rescore) then bf16 activations
  char* RC = carve((size_t)NV * 160 * 4);  // 16,056,320
  unsigned* candq = (unsigned*)RC;
  __bf16* h1 = (__bf16*)RC;                 // 1.6 MB
  __bf16* Y1 = (__bf16*)(RC + 1605632);     // 1.6 MB
  __bf16* h2 = (__bf16*)(RC + 3211264);     // 3.2 MB
  __bf16* Y2 = (__bf16*)(RC + 6422528);     // 3.2 MB

  k_split<<<(NV + 255) / 256, 256, 0, stream>>>(x, xhi, xlo, sqf, cnt, cur);
  k_sweep<<<dim3(98, 4, cB), 128, 0, stream>>>(xhi, xlo, sqf, candq);
  k_rescore<<<NV / 4, 256, 0, stream>>>(x, candq, nbr, cnt);

  k_scan<<<cB, 64, 0, stream>>>(cnt, rp);
  k_fill<<<(NV * cK) / 256, 256, 0, stream>>>(nbr, rp, cur, el);

  k_theta1<<<NV * cH / 256, 256, 0, stream>>>(x, w1, b1, g1, be1, h1);
  k_v2e32<<<NV / 4, 256, 0, stream>>>(h1, nbr, Y1);
  k_e2v_t2<<<NV / 4, 256, 0, stream>>>(Y1, rp, el, w2, b2, g2, be2, h2);
  k_v2e64<<<NV / 4, 256, 0, stream>>>(h2, nbr, Y2);
  k_e2v64<<<NV / 4, 256, 0, stream>>>(Y2, rp, el, out);
}